// Round 4
// baseline (630.277 us; speedup 1.0000x reference)
//
#include <hip/hip_runtime.h>
#include <hip/hip_fp16.h>

#define NN 50000   // nodes
#define NE 100000  // edges
#define NB 512     // graphs
#define NBLK_SCAN 196   // ceil(NN/256)
// H = 64, F_NODE = 16, F_EDGE = 8, T = 3

typedef _Float16 f16x8 __attribute__((ext_vector_type(8)));
typedef float f32x4  __attribute__((ext_vector_type(4)));

__device__ __forceinline__ float sigm(float v) { return 1.0f / (1.0f + __expf(-v)); }
__device__ __forceinline__ float tanh_fast(float v) {
    float e = __expf(-2.0f * fabsf(v));
    float t = (1.0f - e) / (1.0f + e);
    return v < 0.f ? -t : t;
}

// async global->LDS DMA, 16B per lane (dest = uniform base + lane*16)
__device__ __forceinline__ void async_copy16(const void* g, void* l) {
    __builtin_amdgcn_global_load_lds(
        (const __attribute__((address_space(1))) void*)g,
        (__attribute__((address_space(3))) void*)l, 16, 0, 0);
}

// x[n][h] = node_features[n] . Win[h] + bin[h]; also write f16 copy xh
__global__ __launch_bounds__(256) void node_in_kernel(
    const float* __restrict__ nf, const float* __restrict__ Win,
    const float* __restrict__ bin_, float* __restrict__ x, __half* __restrict__ xh)
{
    int idx = blockIdx.x * 256 + threadIdx.x;
    if (idx >= NN * 64) return;
    int n = idx >> 6, h = idx & 63;
    float acc = bin_[h];
    #pragma unroll
    for (int f = 0; f < 16; f++) acc += nf[n * 16 + f] * Win[h * 16 + f];
    x[idx] = acc;
    xh[idx] = __float2half(acc);
}

// ehh[e][k] = f16(relu(edge_features[e] . We1[k] + be1[k]))
__global__ __launch_bounds__(256) void edge_l1_kernel(
    const float* __restrict__ ef, const float* __restrict__ We1,
    const float* __restrict__ be1, __half* __restrict__ ehh)
{
    int idx = blockIdx.x * 256 + threadIdx.x;
    if (idx >= NE * 64) return;
    int e = idx >> 6, k = idx & 63;
    float acc = be1[k];
    #pragma unroll
    for (int f = 0; f < 8; f++) acc += ef[e * 8 + f] * We1[k * 8 + f];
    ehh[idx] = __float2half(fmaxf(acc, 0.0f));
}

// Pack We2 (+ be2 K-extension) into LANE-LINEAR f16 MFMA-B-fragment order:
// Bp[kt*2048 + nt*512 + lane*8 + i]; lane = quad*16 + m;
//   n = nt*16 + m, kk = quad*8 + i, p = kt*32 + kk;
//   p<4096: We2[(n*64 + (p>>6))*64 + (p&63)], else be2[n*64 + (p-4096)]
__global__ __launch_bounds__(256) void pack_b_kernel(
    const float* __restrict__ We2, const float* __restrict__ be2,
    __half* __restrict__ Bp)
{
    int idx = blockIdx.x * 256 + threadIdx.x;
    if (idx >= 130 * 2048) return;
    int i  = idx & 7;
    int l  = (idx >> 3) & 63;
    int nt = (idx >> 9) & 3;
    int kt = idx >> 11;
    int n  = nt * 16 + (l & 15);
    int kk = (l >> 4) * 8 + i;
    int p  = kt * 32 + kk;
    float v;
    if (p < 4096) {
        int j = p >> 6, k = p & 63;
        v = We2[((size_t)(n * 64 + j)) * 64 + k];
    } else {
        v = be2[n * 64 + (p - 4096)];
    }
    Bp[idx] = __float2half(v);
}

// Pack GRU weights into f16 B-frag layout WG[kt][nt][n][kk]:
// cols 0..383 = [i_r,i_z,i_n](Wih) ++ [h_r,h_z,h_n](Whh); nt tile = 16 cols; kt: K=64 in 2x32
__global__ __launch_bounds__(256) void pack_gru_kernel(
    const float* __restrict__ Wih, const float* __restrict__ Whh,
    __half* __restrict__ WG)
{
    int idx = blockIdx.x * 256 + threadIdx.x;   // 2*24*16*32 = 24576
    if (idx >= 24576) return;
    int kk = idx & 31;
    int n  = (idx >> 5) & 15;
    int nt = (idx >> 9) % 24;
    int kt = (idx >> 9) / 24;
    int k = kt * 32 + kk;
    int col192 = (nt % 12) * 16 + n;
    int gate = col192 >> 6, h = col192 & 63;
    const float* src = (nt < 12) ? Wih : Whh;
    WG[idx] = __float2half(src[((size_t)(gate * 64 + h)) * 64 + k]);
}

// ---- counting sort of edges by target (fast parallel scan; runs every launch) ----

// cnt[t] += 1 for each edge
__global__ __launch_bounds__(256) void hist_kernel(
    const int* __restrict__ Etgt, int* __restrict__ cnt)
{
    int e = blockIdx.x * 256 + threadIdx.x;
    if (e < NE) atomicAdd(&cnt[Etgt[e]], 1);
}

// in-block exclusive scan over 256 ints (4 waves, shuffle + tiny LDS)
__device__ __forceinline__ int block_excl_scan(int v, int tid, int* lds)
{
    int lane = tid & 63, w = tid >> 6;
    int incl = v;
    #pragma unroll
    for (int d = 1; d < 64; d <<= 1) {
        int u = __shfl_up(incl, d, 64);
        if (lane >= d) incl += u;
    }
    if (lane == 63) lds[w] = incl;
    __syncthreads();
    if (tid == 0) {
        int a = lds[0], b = lds[1], c = lds[2];
        lds[4] = 0; lds[5] = a; lds[6] = a + b; lds[7] = a + b + c;
    }
    __syncthreads();
    return incl - v + lds[4 + w];
}

// phase A: bsum[b] = sum of cnt[b*256 .. b*256+255]
__global__ __launch_bounds__(256) void scanA_kernel(
    const int* __restrict__ cnt, int* __restrict__ bsum)
{
    __shared__ int s4[4];
    int tid = threadIdx.x;
    int idx = blockIdx.x * 256 + tid;
    int v = (idx < NN) ? cnt[idx] : 0;
    #pragma unroll
    for (int d = 1; d < 64; d <<= 1) v += __shfl_xor(v, d, 64);
    if ((tid & 63) == 0) s4[tid >> 6] = v;
    __syncthreads();
    if (tid == 0) bsum[blockIdx.x] = s4[0] + s4[1] + s4[2] + s4[3];
}

// phase B: exclusive scan of bsum[0..NBLK_SCAN) -> bscan; off[NN] = total
__global__ __launch_bounds__(256) void scanB_kernel(
    const int* __restrict__ bsum, int* __restrict__ bscan, int* __restrict__ off)
{
    __shared__ int lds[8];
    int tid = threadIdx.x;
    int v = (tid < NBLK_SCAN) ? bsum[tid] : 0;
    int ex = block_excl_scan(v, tid, lds);
    if (tid < NBLK_SCAN) bscan[tid] = ex;
    if (tid == NBLK_SCAN) off[NN] = ex;   // total
}

// phase C: off[idx] = wpos[idx] = bscan[blk] + excl-scan within block
__global__ __launch_bounds__(256) void scanC_kernel(
    const int* __restrict__ cnt, const int* __restrict__ bscan,
    int* __restrict__ off, int* __restrict__ wpos)
{
    __shared__ int lds[8];
    int tid = threadIdx.x;
    int idx = blockIdx.x * 256 + tid;
    int v = (idx < NN) ? cnt[idx] : 0;
    int ex = block_excl_scan(v, tid, lds) + bscan[blockIdx.x];
    if (idx < NN) { off[idx] = ex; wpos[idx] = ex; }
}

// inv[e] = position of edge e in target-sorted order; tgt_sorted[p] = its target
__global__ __launch_bounds__(256) void scatter_kernel(
    const int* __restrict__ Etgt, int* __restrict__ wpos,
    int* __restrict__ inv, int* __restrict__ tgt_sorted)
{
    int e = blockIdx.x * 256 + threadIdx.x;
    if (e < NE) {
        int t = Etgt[e];
        int p = atomicAdd(&wpos[t], 1);
        inv[e] = p;
        tgt_sorted[p] = t;
    }
}

// Fused message GEMM, f16: msg[e][i] = sum_{j,k} We2[i*64+j][k]*x[src][j]*eh[e][k] (+be2.x)
// v4: 64 edges/WAVE (halves the per-edge LDS B-read cost vs 32), 2-wave/128-edge
// blocks (782 blocks, 3/CU, 51.7KB LDS), BK=128 double-buffered B via
// global_load_lds DMA (no ds_write, no prefetch VGPRs). No atomics in epilogue.
__global__ __launch_bounds__(128, 1) void msg_kernel(
    const __half* __restrict__ xh, const __half* __restrict__ ehh,
    const __half* __restrict__ Bp,
    const int* __restrict__ Esrc, const int* __restrict__ inv,
    float* __restrict__ msgf)
{
    __shared__ __align__(16) __half xs[2][64][72];   // 18,432 B
    __shared__ __align__(16) __half bbuf[2][8192];   // 32,768 B: [buf][2 j-tiles]
    __shared__ int inv_s[128];
    const int tid = threadIdx.x;
    const int e0 = blockIdx.x * 128;
    const int w = tid >> 6, lane = tid & 63;
    const int m = lane & 15, quad = lane >> 4;

    {   // stage gathered f16 source rows: thread tid -> row tid (128B)
        const int e = e0 + tid;
        const bool ok = (e < NE);
        const int src = ok ? Esrc[e] : 0;
        inv_s[tid] = ok ? inv[e] : 0;
        const uint4* xsrc = (const uint4*)(xh + (size_t)src * 64);
        __half* dst = &xs[w][tid & 63][0];
        #pragma unroll
        for (int i = 0; i < 8; i++) {
            uint4 v = ok ? xsrc[i] : make_uint4(0, 0, 0, 0);
            *(uint4*)(dst + i * 8) = v;
        }
    }

    // prologue: DMA tile-pair 0 (kt 0..3, 16KB) -> bbuf[0]; wave w stages its 8KB
    {
        const __half* gp = Bp + (size_t)w * 4096 + lane * 8;
        #pragma unroll
        for (int i = 0; i < 8; i++)
            async_copy16(gp + i * 512, &bbuf[0][w * 4096 + i * 512]);
    }

    // per-lane eh f16 cache: k in {quad*8..+8} u {32+quad*8..+8}, 4 m-tiles
    __half2 ehc2[4][2][4];
    #pragma unroll
    for (int mt = 0; mt < 4; mt++) {
        const int e = e0 + w * 64 + mt * 16 + m;
        if (e < NE) {
            union { uint4 u; __half2 h[4]; } u0, u1;
            u0.u = *(const uint4*)(ehh + (size_t)e * 64 + quad * 8);
            u1.u = *(const uint4*)(ehh + (size_t)e * 64 + 32 + quad * 8);
            #pragma unroll
            for (int q = 0; q < 4; q++) { ehc2[mt][0][q] = u0.h[q]; ehc2[mt][1][q] = u1.h[q]; }
        } else {
            __half2 z = __halves2half2(__float2half(0.f), __float2half(0.f));
            #pragma unroll
            for (int q = 0; q < 4; q++) { ehc2[mt][0][q] = z; ehc2[mt][1][q] = z; }
        }
    }

    f32x4 acc[4][4];
    #pragma unroll
    for (int a = 0; a < 4; a++)
        #pragma unroll
        for (int b = 0; b < 4; b++)
            #pragma unroll
            for (int q = 0; q < 4; q++) acc[a][b][q] = 0.f;

    __syncthreads();   // xs + bbuf[0] ready (barrier drains vmcnt)

    int cur = 0;
    #pragma unroll 1
    for (int it = 0; it < 32; it++) {
        // DMA next tile-pair into the other buffer (lands during MFMA phase)
        if (it < 31) {
            const __half* gp = Bp + (size_t)(it + 1) * 8192 + w * 4096 + lane * 8;
            #pragma unroll
            for (int i = 0; i < 8; i++)
                async_copy16(gp + i * 512, &bbuf[cur ^ 1][w * 4096 + i * 512]);
        } else {
            // tail: be2 K-extension tile (kt 128,129 = 4096 f16); wave w stages 2KB
            const __half* gp = Bp + (size_t)128 * 2048 + w * 2048 + lane * 8;
            #pragma unroll
            for (int i = 0; i < 4; i++)
                async_copy16(gp + i * 512, &bbuf[cur ^ 1][w * 2048 + i * 512]);
        }

        #pragma unroll
        for (int jj = 0; jj < 2; jj++) {
            const int j = 2 * it + jj;
            __half2 xsj2[4];
            #pragma unroll
            for (int mt = 0; mt < 4; mt++) {
                __half v = xs[w][mt * 16 + m][j];
                xsj2[mt] = __halves2half2(v, v);
            }
            #pragma unroll
            for (int half = 0; half < 2; half++) {
                f16x8 bf[4];
                #pragma unroll
                for (int nt = 0; nt < 4; nt++)
                    bf[nt] = *(const f16x8*)(&bbuf[cur][jj * 4096 + half * 2048 + nt * 512 + lane * 8]);
                #pragma unroll
                for (int mt = 0; mt < 4; mt++) {
                    union { __half2 h[4]; f16x8 v; } u;
                    #pragma unroll
                    for (int q = 0; q < 4; q++)
                        u.h[q] = __hmul2(xsj2[mt], ehc2[mt][half][q]);
                    #pragma unroll
                    for (int nt = 0; nt < 4; nt++)
                        acc[mt][nt] = __builtin_amdgcn_mfma_f32_16x16x32_f16(
                            u.v, bf[nt], acc[mt][nt], 0, 0, 0);
                }
            }
        }
        __syncthreads();   // drains DMA (vmcnt) + all waves done reading bbuf[cur]
        cur ^= 1;
    }

    // be2 K-extension (kt = 128,129, staged in bbuf[cur]): A = xs row chunk
    #pragma unroll
    for (int half = 0; half < 2; half++) {
        f16x8 bf[4];
        #pragma unroll
        for (int nt = 0; nt < 4; nt++)
            bf[nt] = *(const f16x8*)(&bbuf[cur][half * 2048 + nt * 512 + lane * 8]);
        #pragma unroll
        for (int mt = 0; mt < 4; mt++) {
            f16x8 af = *(const f16x8*)(&xs[w][mt * 16 + m][half * 32 + quad * 8]);
            #pragma unroll
            for (int nt = 0; nt < 4; nt++)
                acc[mt][nt] = __builtin_amdgcn_mfma_f32_16x16x32_f16(
                    af, bf[nt], acc[mt][nt], 0, 0, 0);
        }
    }

    // C layout: col = lane&15 (i), row = quad*4 + reg (edge in tile)
    // plain stores to target-sorted msgf rows
    #pragma unroll
    for (int mt = 0; mt < 4; mt++) {
        #pragma unroll
        for (int r = 0; r < 4; r++) {
            const int row = w * 64 + mt * 16 + quad * 4 + r;
            const int e = e0 + row;
            if (e < NE) {
                const size_t base = (size_t)inv_s[row] * 64 + m;
                #pragma unroll
                for (int nt = 0; nt < 4; nt++)
                    msgf[base + nt * 16] = acc[mt][nt][r];
            }
        }
    }
}

// GRU via MFMA, v4: row-parallel segment-sum (all 4 waves stream the block's
// contiguous msgf rows, LDS-atomic into aggs), then wave = 16 nodes x 384
// gate-cols (K=64). Weights LDS-staged once/block.
__global__ __launch_bounds__(256, 2) void gru_kernel(
    const float* __restrict__ msgf, const int* __restrict__ off,
    const int* __restrict__ tgt_sorted,
    float* __restrict__ x, __half* __restrict__ xh,
    const __half* __restrict__ WG,
    const float* __restrict__ bih, const float* __restrict__ bhh)
{
    __shared__ __half wlds[24576];   // 48 KB
    __shared__ float aggs[64][68];   // 17.4 KB
    const int tid = threadIdx.x;
    {
        const uint4* src = (const uint4*)WG;
        uint4* dst = (uint4*)wlds;
        #pragma unroll
        for (int i = 0; i < 12; i++) dst[i * 256 + tid] = src[i * 256 + tid];
    }
    {   // zero aggs (64*68 = 4352 floats = 17 per thread)
        float* a = &aggs[0][0];
        #pragma unroll
        for (int i = 0; i < 17; i++) a[i * 256 + tid] = 0.f;
    }
    __syncthreads();

    const int w = tid >> 6, lane = tid & 63, m = lane & 15, quad = lane >> 4;
    const int nb0 = blockIdx.x * 64;
    const int hi = (nb0 + 64 < NN) ? nb0 + 64 : NN;

    // row-parallel segment-sum over contiguous sorted rows [off[nb0], off[hi])
    {
        const int r0 = off[nb0], r1 = off[hi];
        for (int p = r0 + w; p < r1; p += 4) {
            float v = msgf[(size_t)p * 64 + lane];
            int t = tgt_sorted[p];
            atomicAdd(&aggs[t - nb0][lane], v);
        }
    }
    __syncthreads();

    const int nbase = nb0 + w * 16;
    const int anode = nbase + m;           // A-operand row
    const bool aok = (anode < NN);

    f16x8 a_agg[2], a_x[2];
    #pragma unroll
    for (int kt = 0; kt < 2; kt++) {
        const int koff = kt * 32 + quad * 8;
        {
            const float* ap = &aggs[w * 16 + m][koff];
            float4 f0 = *(const float4*)ap;
            float4 f1 = *(const float4*)(ap + 4);
            union { __half2 h[4]; f16x8 v; } u;
            u.h[0] = __floats2half2_rn(f0.x, f0.y);
            u.h[1] = __floats2half2_rn(f0.z, f0.w);
            u.h[2] = __floats2half2_rn(f1.x, f1.y);
            u.h[3] = __floats2half2_rn(f1.z, f1.w);
            a_agg[kt] = u.v;
        }
        if (aok) {
            a_x[kt] = *(const f16x8*)(xh + (size_t)anode * 64 + koff);
        } else {
            f16x8 z;
            #pragma unroll
            for (int i = 0; i < 8; i++) z[i] = (_Float16)0;
            a_x[kt] = z;
        }
    }

    f32x4 acc[24];
    #pragma unroll
    for (int nt = 0; nt < 24; nt++)
        #pragma unroll
        for (int q = 0; q < 4; q++) acc[nt][q] = 0.f;

    #pragma unroll
    for (int kt = 0; kt < 2; kt++) {
        #pragma unroll
        for (int nt = 0; nt < 24; nt++) {
            f16x8 b = *(const f16x8*)(wlds + (kt * 24 + nt) * 512 + m * 32 + quad * 8);
            acc[nt] = __builtin_amdgcn_mfma_f32_16x16x32_f16(
                (nt < 12) ? a_agg[kt] : a_x[kt], b, acc[nt], 0, 0, 0);
        }
    }

    // epilogue: node = quad*4 + r (C row), h = t*16 + m (C col)
    #pragma unroll
    for (int t = 0; t < 4; t++) {
        const int h = t * 16 + m;
        const float bir = bih[h], biz = bih[64 + h], bin = bih[128 + h];
        const float bhr = bhh[h], bhz = bhh[64 + h], bhn = bhh[128 + h];
        #pragma unroll
        for (int r = 0; r < 4; r++) {
            const int nd = nbase + quad * 4 + r;
            if (nd >= NN) continue;
            float ir  = acc[t][r]      + bir;
            float iz  = acc[4 + t][r]  + biz;
            float in_ = acc[8 + t][r]  + bin;
            float hr  = acc[12 + t][r] + bhr;
            float hz  = acc[16 + t][r] + bhz;
            float hn  = acc[20 + t][r] + bhn;
            float rg = sigm(ir + hr);
            float z  = sigm(iz + hz);
            float n  = tanh_fast(in_ + rg * hn);
            float xold = x[(size_t)nd * 64 + h];
            float xn = (1.0f - z) * n + z * xold;
            x[(size_t)nd * 64 + h] = xn;
            xh[(size_t)nd * 64 + h] = __float2half(xn);
        }
    }
}

// out[n] = x[n].Wout + bout; pooled[batch[n]] += out[n]
__global__ __launch_bounds__(256) void pool_kernel(
    const float* __restrict__ x, const float* __restrict__ Wout,
    const float* __restrict__ bout, const int* __restrict__ batch,
    float* __restrict__ out)
{
    const int node = blockIdx.x * 256 + threadIdx.x;
    if (node >= NN) return;
    float acc = bout[0];
    const float4* xp = (const float4*)(x + (size_t)node * 64);
    #pragma unroll
    for (int i = 0; i < 16; i++) {
        float4 v = xp[i];
        acc += v.x * Wout[4*i] + v.y * Wout[4*i+1] + v.z * Wout[4*i+2] + v.w * Wout[4*i+3];
    }
    atomicAdd(out + batch[node], acc);
}

extern "C" void kernel_launch(void* const* d_in, const int* in_sizes, int n_in,
                              void* d_out, int out_size, void* d_ws, size_t ws_size,
                              hipStream_t stream)
{
    const float* nf   = (const float*)d_in[0];
    const float* ef   = (const float*)d_in[1];
    const int*   Esrc = (const int*)  d_in[2];
    const int*   Etgt = (const int*)  d_in[3];
    const int*   bat  = (const int*)  d_in[4];
    const float* Win  = (const float*)d_in[5];
    const float* bin_ = (const float*)d_in[6];
    const float* We1  = (const float*)d_in[7];
    const float* be1  = (const float*)d_in[8];
    const float* We2  = (const float*)d_in[9];
    const float* be2  = (const float*)d_in[10];
    const float* Wih  = (const float*)d_in[11];
    const float* bih  = (const float*)d_in[12];
    const float* Whh  = (const float*)d_in[13];
    const float* bhh  = (const float*)d_in[14];
    const float* Wout = (const float*)d_in[15];
    const float* bout = (const float*)d_in[16];

    char* ws = (char*)d_ws;
    float*  x          = (float*)(ws);                // 12,800,000 B
    float*  msgf       = (float*)(ws + 12800000);     // 25,600,000 B
    __half* xh         = (__half*)(ws + 38400000);    //  6,400,000 B
    __half* ehh        = (__half*)(ws + 44800000);    // 12,800,000 B
    __half* Bp         = (__half*)(ws + 57600000);    //    532,480 B
    __half* WG         = (__half*)(ws + 58132480);    //     49,152 B
    int*    cnt        = (int*)   (ws + 58181632);    //    200,016 B
    int*    off        = (int*)   (ws + 58381648);    //    200,016 B
    int*    wpos       = (int*)   (ws + 58581664);    //    200,016 B
    int*    inv        = (int*)   (ws + 58781680);    //    400,000 B
    int*    tgt_sorted = (int*)   (ws + 59181680);    //    400,000 B
    int*    bsum       = (int*)   (ws + 59581680);    //      1,024 B
    int*    bscan      = (int*)   (ws + 59582704);    //      1,024 B

    hipMemsetAsync(d_out, 0, NB * sizeof(float), stream);
    hipMemsetAsync(cnt, 0, (NN + 1) * sizeof(int), stream);

    node_in_kernel<<<(NN * 64 + 255) / 256, 256, 0, stream>>>(nf, Win, bin_, x, xh);
    edge_l1_kernel<<<(NE * 64 + 255) / 256, 256, 0, stream>>>(ef, We1, be1, ehh);
    pack_b_kernel<<<(130 * 2048 + 255) / 256, 256, 0, stream>>>(We2, be2, Bp);
    pack_gru_kernel<<<(24576 + 255) / 256, 256, 0, stream>>>(Wih, Whh, WG);

    hist_kernel<<<(NE + 255) / 256, 256, 0, stream>>>(Etgt, cnt);
    scanA_kernel<<<NBLK_SCAN, 256, 0, stream>>>(cnt, bsum);
    scanB_kernel<<<1, 256, 0, stream>>>(bsum, bscan, off);
    scanC_kernel<<<NBLK_SCAN, 256, 0, stream>>>(cnt, bscan, off, wpos);
    scatter_kernel<<<(NE + 255) / 256, 256, 0, stream>>>(Etgt, wpos, inv, tgt_sorted);

    for (int t = 0; t < 3; t++) {
        msg_kernel<<<(NE + 127) / 128, 128, 0, stream>>>(xh, ehh, Bp, Esrc, inv, msgf);
        gru_kernel<<<(NN + 63) / 64, 256, 0, stream>>>(msgf, off, tgt_sorted, x, xh, WG, bih, bhh);
    }

    pool_kernel<<<(NN + 255) / 256, 256, 0, stream>>>(x, Wout, bout, bat, (float*)d_out);
}

// Round 5
// 592.173 us; speedup vs baseline: 1.0643x; 1.0643x over previous
//
#include <hip/hip_runtime.h>
#include <hip/hip_fp16.h>

#define NN 50000   // nodes
#define NE 100000  // edges
#define NB 512     // graphs
#define NBLK_SCAN 196   // ceil(NN/256)
// H = 64, F_NODE = 16, F_EDGE = 8, T = 3

typedef _Float16 f16x8 __attribute__((ext_vector_type(8)));
typedef float f32x4  __attribute__((ext_vector_type(4)));

__device__ __forceinline__ float sigm(float v) { return 1.0f / (1.0f + __expf(-v)); }
__device__ __forceinline__ float tanh_fast(float v) {
    float e = __expf(-2.0f * fabsf(v));
    float t = (1.0f - e) / (1.0f + e);
    return v < 0.f ? -t : t;
}

// async global->LDS DMA, 16B per lane (lds dest = wave-uniform base + lane*16)
__device__ __forceinline__ void async_copy16(const void* g, void* l) {
    __builtin_amdgcn_global_load_lds(
        (const __attribute__((address_space(1))) void*)g,
        (__attribute__((address_space(3))) void*)l, 16, 0, 0);
}

// x[n][h] = node_features[n] . Win[h] + bin[h]; also write f16 copy xh
__global__ __launch_bounds__(256) void node_in_kernel(
    const float* __restrict__ nf, const float* __restrict__ Win,
    const float* __restrict__ bin_, float* __restrict__ x, __half* __restrict__ xh)
{
    int idx = blockIdx.x * 256 + threadIdx.x;
    if (idx >= NN * 64) return;
    int n = idx >> 6, h = idx & 63;
    float acc = bin_[h];
    #pragma unroll
    for (int f = 0; f < 16; f++) acc += nf[n * 16 + f] * Win[h * 16 + f];
    x[idx] = acc;
    xh[idx] = __float2half(acc);
}

// ehh[e][k] = f16(relu(edge_features[e] . We1[k] + be1[k]))
__global__ __launch_bounds__(256) void edge_l1_kernel(
    const float* __restrict__ ef, const float* __restrict__ We1,
    const float* __restrict__ be1, __half* __restrict__ ehh)
{
    int idx = blockIdx.x * 256 + threadIdx.x;
    if (idx >= NE * 64) return;
    int e = idx >> 6, k = idx & 63;
    float acc = be1[k];
    #pragma unroll
    for (int f = 0; f < 8; f++) acc += ef[e * 8 + f] * We1[k * 8 + f];
    ehh[idx] = __float2half(fmaxf(acc, 0.0f));
}

// Pack We2 (+ be2 K-extension) into LANE-LINEAR f16 MFMA-B-fragment order:
// Bp[kt*2048 + nt*512 + lane*8 + i]; lane = quad*16 + m;
//   n = nt*16 + m, kk = quad*8 + i, p = kt*32 + kk;
//   p<4096: We2[(n*64 + (p>>6))*64 + (p&63)], else be2[n*64 + (p-4096)]
__global__ __launch_bounds__(256) void pack_b_kernel(
    const float* __restrict__ We2, const float* __restrict__ be2,
    __half* __restrict__ Bp)
{
    int idx = blockIdx.x * 256 + threadIdx.x;
    if (idx >= 130 * 2048) return;
    int i  = idx & 7;
    int l  = (idx >> 3) & 63;
    int nt = (idx >> 9) & 3;
    int kt = idx >> 11;
    int n  = nt * 16 + (l & 15);
    int kk = (l >> 4) * 8 + i;
    int p  = kt * 32 + kk;
    float v;
    if (p < 4096) {
        int j = p >> 6, k = p & 63;
        v = We2[((size_t)(n * 64 + j)) * 64 + k];
    } else {
        v = be2[n * 64 + (p - 4096)];
    }
    Bp[idx] = __float2half(v);
}

// Pack GRU weights into f16 B-frag layout WG[kt][nt][n][kk]:
// cols 0..383 = [i_r,i_z,i_n](Wih) ++ [h_r,h_z,h_n](Whh); nt tile = 16 cols; kt: K=64 in 2x32
__global__ __launch_bounds__(256) void pack_gru_kernel(
    const float* __restrict__ Wih, const float* __restrict__ Whh,
    __half* __restrict__ WG)
{
    int idx = blockIdx.x * 256 + threadIdx.x;   // 2*24*16*32 = 24576
    if (idx >= 24576) return;
    int kk = idx & 31;
    int n  = (idx >> 5) & 15;
    int nt = (idx >> 9) % 24;
    int kt = (idx >> 9) / 24;
    int k = kt * 32 + kk;
    int col192 = (nt % 12) * 16 + n;
    int gate = col192 >> 6, h = col192 & 63;
    const float* src = (nt < 12) ? Wih : Whh;
    WG[idx] = __float2half(src[((size_t)(gate * 64 + h)) * 64 + k]);
}

// ---- counting sort of edges by target (fast parallel scan; runs every launch) ----

__global__ __launch_bounds__(256) void hist_kernel(
    const int* __restrict__ Etgt, int* __restrict__ cnt)
{
    int e = blockIdx.x * 256 + threadIdx.x;
    if (e < NE) atomicAdd(&cnt[Etgt[e]], 1);
}

// in-block exclusive scan over 256 ints (4 waves, shuffle + tiny LDS)
__device__ __forceinline__ int block_excl_scan(int v, int tid, int* lds)
{
    int lane = tid & 63, w = tid >> 6;
    int incl = v;
    #pragma unroll
    for (int d = 1; d < 64; d <<= 1) {
        int u = __shfl_up(incl, d, 64);
        if (lane >= d) incl += u;
    }
    if (lane == 63) lds[w] = incl;
    __syncthreads();
    if (tid == 0) {
        int a = lds[0], b = lds[1], c = lds[2];
        lds[4] = 0; lds[5] = a; lds[6] = a + b; lds[7] = a + b + c;
    }
    __syncthreads();
    return incl - v + lds[4 + w];
}

// phase A: bsum[b] = sum of cnt[b*256 .. b*256+255]
__global__ __launch_bounds__(256) void scanA_kernel(
    const int* __restrict__ cnt, int* __restrict__ bsum)
{
    __shared__ int s4[4];
    int tid = threadIdx.x;
    int idx = blockIdx.x * 256 + tid;
    int v = (idx < NN) ? cnt[idx] : 0;
    #pragma unroll
    for (int d = 1; d < 64; d <<= 1) v += __shfl_xor(v, d, 64);
    if ((tid & 63) == 0) s4[tid >> 6] = v;
    __syncthreads();
    if (tid == 0) bsum[blockIdx.x] = s4[0] + s4[1] + s4[2] + s4[3];
}

// phase B: exclusive scan of bsum[0..NBLK_SCAN) -> bscan; off[NN] = total
__global__ __launch_bounds__(256) void scanB_kernel(
    const int* __restrict__ bsum, int* __restrict__ bscan, int* __restrict__ off)
{
    __shared__ int lds[8];
    int tid = threadIdx.x;
    int v = (tid < NBLK_SCAN) ? bsum[tid] : 0;
    int ex = block_excl_scan(v, tid, lds);
    if (tid < NBLK_SCAN) bscan[tid] = ex;
    if (tid == NBLK_SCAN) off[NN] = ex;   // total
}

// phase C: off[idx] = wpos[idx] = bscan[blk] + excl-scan within block
__global__ __launch_bounds__(256) void scanC_kernel(
    const int* __restrict__ cnt, const int* __restrict__ bscan,
    int* __restrict__ off, int* __restrict__ wpos)
{
    __shared__ int lds[8];
    int tid = threadIdx.x;
    int idx = blockIdx.x * 256 + tid;
    int v = (idx < NN) ? cnt[idx] : 0;
    int ex = block_excl_scan(v, tid, lds) + bscan[blockIdx.x];
    if (idx < NN) { off[idx] = ex; wpos[idx] = ex; }
}

// inv[e] = position of edge e in target-sorted order; tgt_sorted[p] = its target
__global__ __launch_bounds__(256) void scatter_kernel(
    const int* __restrict__ Etgt, int* __restrict__ wpos,
    int* __restrict__ inv, int* __restrict__ tgt_sorted)
{
    int e = blockIdx.x * 256 + threadIdx.x;
    if (e < NE) {
        int t = Etgt[e];
        int p = atomicAdd(&wpos[t], 1);
        inv[e] = p;
        tgt_sorted[p] = t;
    }
}

// Fused message GEMM, f16: msg[e][i] = sum_{j,k} We2[i*64+j][k]*x[src][j]*eh[e][k] (+be2.x)
// v5 (k-split): block = 256 thr = 4 waves = 2 edge-groups (eg) x 2 k-halves (kg);
// 128 edges/block -> grid 782 (3 blocks/CU, 12 waves/CU). Wave (eg,kg) computes
// the partial over k in [kg*32, kg*32+32) for 64 edges: per j it reads only ONE
// B-fragment set (kt = 2j+kg) -> per-wave LDS B-reads halved vs R3 while MFMA
// count/wave is unchanged. BK=128 double-buffer staged via global_load_lds DMA
// (32 barriers). k-halves merged by a pairwise f32x4 LDS reduction (overlaid on
// the dead xs/bbuf arena), then kg=0 waves do the plain-store epilogue.
__global__ __launch_bounds__(256, 3) void msg_kernel(
    const __half* __restrict__ xh, const __half* __restrict__ ehh,
    const __half* __restrict__ Bp,
    const int* __restrict__ Esrc, const int* __restrict__ inv,
    float* __restrict__ msgf)
{
    // arena: xs [2][64][72] f16 (18432 B) ++ bbuf [2][8192] f16 (32768 B);
    // reduction overlays the first 32768 B after the j-loop is done.
    __shared__ __align__(16) unsigned char arena[18432 + 32768];
    __shared__ int inv_s[128];
    __half (*xs)[64][72] = (__half(*)[64][72])arena;
    __half (*bbuf)[8192] = (__half(*)[8192])(arena + 18432);
    f32x4* red = (f32x4*)arena;   // [2 eg][16 chunk][64 lane] f32x4 = 32 KB

    const int tid = threadIdx.x;
    const int e0 = blockIdx.x * 128;
    const int w = tid >> 6, lane = tid & 63;
    const int m = lane & 15, quad = lane >> 4;
    const int eg = w >> 1, kg = w & 1;

    {   // stage gathered f16 source rows: 128 rows, 2 threads per row (64B each)
        const int r = tid >> 1, part = tid & 1;
        const int e = e0 + r;
        const bool ok = (e < NE);
        const int src = ok ? Esrc[e] : 0;
        if (part == 0) inv_s[r] = ok ? inv[e] : 0;
        const uint4* xsrc = (const uint4*)(xh + (size_t)src * 64 + part * 32);
        __half* dst = &xs[r >> 6][r & 63][part * 32];
        #pragma unroll
        for (int i = 0; i < 4; i++) {
            uint4 v = ok ? xsrc[i] : make_uint4(0, 0, 0, 0);
            *(uint4*)(dst + i * 8) = v;
        }
    }

    // prologue: DMA B tile 0 (kt 0..3, 16 KB) -> bbuf[0]; wave w stages 4 KB
    {
        const __half* gp = Bp + (size_t)w * 2048 + lane * 8;
        #pragma unroll
        for (int i = 0; i < 4; i++)
            async_copy16(gp + i * 512, &bbuf[0][w * 2048 + i * 512]);
    }

    // per-lane eh cache for this wave's k-half only: 4 m-tiles x 4 half2
    __half2 ehc2[4][4];
    #pragma unroll
    for (int mt = 0; mt < 4; mt++) {
        const int e = e0 + eg * 64 + mt * 16 + m;
        if (e < NE) {
            union { uint4 u; __half2 h[4]; } u0;
            u0.u = *(const uint4*)(ehh + (size_t)e * 64 + kg * 32 + quad * 8);
            #pragma unroll
            for (int q = 0; q < 4; q++) ehc2[mt][q] = u0.h[q];
        } else {
            __half2 z = __halves2half2(__float2half(0.f), __float2half(0.f));
            #pragma unroll
            for (int q = 0; q < 4; q++) ehc2[mt][q] = z;
        }
    }

    f32x4 acc[4][4];
    #pragma unroll
    for (int a = 0; a < 4; a++)
        #pragma unroll
        for (int b = 0; b < 4; b++)
            #pragma unroll
            for (int q = 0; q < 4; q++) acc[a][b][q] = 0.f;

    __syncthreads();   // xs + bbuf[0] ready (barrier drains DMA vmcnt)

    int cur = 0;
    #pragma unroll 1
    for (int it = 0; it < 32; it++) {
        // DMA next tile (16 KB, kt 4(it+1)..+3) or the 8 KB be2 tail tile
        if (it < 31) {
            const __half* gp = Bp + (size_t)(it + 1) * 8192 + w * 2048 + lane * 8;
            #pragma unroll
            for (int i = 0; i < 4; i++)
                async_copy16(gp + i * 512, &bbuf[cur ^ 1][w * 2048 + i * 512]);
        } else {
            const __half* gp = Bp + (size_t)128 * 2048 + w * 1024 + lane * 8;
            #pragma unroll
            for (int i = 0; i < 2; i++)
                async_copy16(gp + i * 512, &bbuf[cur ^ 1][w * 1024 + i * 512]);
        }

        #pragma unroll
        for (int jj = 0; jj < 2; jj++) {
            // B fragments for kt = 4*it + 2*jj + kg (this wave's k-half only)
            const int ktl = 2 * jj + kg;
            f16x8 bf[4];
            #pragma unroll
            for (int nt = 0; nt < 4; nt++)
                bf[nt] = *(const f16x8*)(&bbuf[cur][ktl * 2048 + nt * 512 + lane * 8]);
            #pragma unroll
            for (int mt = 0; mt < 4; mt++) {
                const __half2 xp = *(const __half2*)(&xs[eg][mt * 16 + m][2 * it]);
                const __half xv = (jj == 0) ? __low2half(xp) : __high2half(xp);
                const __half2 xsj2 = __half2half2(xv);
                union { __half2 h[4]; f16x8 v; } u;
                #pragma unroll
                for (int q = 0; q < 4; q++)
                    u.h[q] = __hmul2(xsj2, ehc2[mt][q]);
                #pragma unroll
                for (int nt = 0; nt < 4; nt++)
                    acc[mt][nt] = __builtin_amdgcn_mfma_f32_16x16x32_f16(
                        u.v, bf[nt], acc[mt][nt], 0, 0, 0);
            }
        }
        __syncthreads();   // drains DMA (vmcnt) + all waves done reading bbuf[cur]
        cur ^= 1;
    }

    // be2 K-extension (kt = 128+kg, staged in bbuf[cur]): A = xs k-half chunk
    {
        f16x8 bf[4];
        #pragma unroll
        for (int nt = 0; nt < 4; nt++)
            bf[nt] = *(const f16x8*)(&bbuf[cur][kg * 2048 + nt * 512 + lane * 8]);
        #pragma unroll
        for (int mt = 0; mt < 4; mt++) {
            f16x8 af = *(const f16x8*)(&xs[eg][mt * 16 + m][kg * 32 + quad * 8]);
            #pragma unroll
            for (int nt = 0; nt < 4; nt++)
                acc[mt][nt] = __builtin_amdgcn_mfma_f32_16x16x32_f16(
                    af, bf[nt], acc[mt][nt], 0, 0, 0);
        }
    }

    // merge k-halves: kg=1 writes partials (lane-linear f32x4), kg=0 adds
    __syncthreads();   // all xs/bbuf reads done -> safe to overlay red
    if (kg == 1) {
        #pragma unroll
        for (int mt = 0; mt < 4; mt++)
            #pragma unroll
            for (int nt = 0; nt < 4; nt++)
                red[eg * 1024 + (mt * 4 + nt) * 64 + lane] = acc[mt][nt];
    }
    __syncthreads();

    if (kg == 0) {
        #pragma unroll
        for (int mt = 0; mt < 4; mt++) {
            #pragma unroll
            for (int nt = 0; nt < 4; nt++) {
                f32x4 p = red[eg * 1024 + (mt * 4 + nt) * 64 + lane];
                #pragma unroll
                for (int q = 0; q < 4; q++) acc[mt][nt][q] += p[q];
            }
        }
        // C layout: col = lane&15 (i), row = quad*4 + reg (edge in tile)
        // plain stores to target-sorted msgf rows
        #pragma unroll
        for (int mt = 0; mt < 4; mt++) {
            #pragma unroll
            for (int r = 0; r < 4; r++) {
                const int row = eg * 64 + mt * 16 + quad * 4 + r;
                const int e = e0 + row;
                if (e < NE) {
                    const size_t base = (size_t)inv_s[row] * 64 + m;
                    #pragma unroll
                    for (int nt = 0; nt < 4; nt++)
                        msgf[base + nt * 16] = acc[mt][nt][r];
                }
            }
        }
    }
}

// GRU via MFMA: row-parallel segment-sum (all 4 waves stream the block's
// contiguous msgf rows, LDS-atomic into aggs), then wave = 16 nodes x 384
// gate-cols (K=64). Weights LDS-staged once/block.
__global__ __launch_bounds__(256, 2) void gru_kernel(
    const float* __restrict__ msgf, const int* __restrict__ off,
    const int* __restrict__ tgt_sorted,
    float* __restrict__ x, __half* __restrict__ xh,
    const __half* __restrict__ WG,
    const float* __restrict__ bih, const float* __restrict__ bhh)
{
    __shared__ __half wlds[24576];   // 48 KB
    __shared__ float aggs[64][68];   // 17.4 KB
    const int tid = threadIdx.x;
    {
        const uint4* src = (const uint4*)WG;
        uint4* dst = (uint4*)wlds;
        #pragma unroll
        for (int i = 0; i < 12; i++) dst[i * 256 + tid] = src[i * 256 + tid];
    }
    {   // zero aggs (64*68 = 4352 floats = 17 per thread)
        float* a = &aggs[0][0];
        #pragma unroll
        for (int i = 0; i < 17; i++) a[i * 256 + tid] = 0.f;
    }
    __syncthreads();

    const int w = tid >> 6, lane = tid & 63, m = lane & 15, quad = lane >> 4;
    const int nb0 = blockIdx.x * 64;
    const int hi = (nb0 + 64 < NN) ? nb0 + 64 : NN;

    // row-parallel segment-sum over contiguous sorted rows [off[nb0], off[hi])
    {
        const int r0 = off[nb0], r1 = off[hi];
        for (int p = r0 + w; p < r1; p += 4) {
            float v = msgf[(size_t)p * 64 + lane];
            int t = tgt_sorted[p];
            atomicAdd(&aggs[t - nb0][lane], v);
        }
    }
    __syncthreads();

    const int nbase = nb0 + w * 16;
    const int anode = nbase + m;           // A-operand row
    const bool aok = (anode < NN);

    f16x8 a_agg[2], a_x[2];
    #pragma unroll
    for (int kt = 0; kt < 2; kt++) {
        const int koff = kt * 32 + quad * 8;
        {
            const float* ap = &aggs[w * 16 + m][koff];
            float4 f0 = *(const float4*)ap;
            float4 f1 = *(const float4*)(ap + 4);
            union { __half2 h[4]; f16x8 v; } u;
            u.h[0] = __floats2half2_rn(f0.x, f0.y);
            u.h[1] = __floats2half2_rn(f0.z, f0.w);
            u.h[2] = __floats2half2_rn(f1.x, f1.y);
            u.h[3] = __floats2half2_rn(f1.z, f1.w);
            a_agg[kt] = u.v;
        }
        if (aok) {
            a_x[kt] = *(const f16x8*)(xh + (size_t)anode * 64 + koff);
        } else {
            f16x8 z;
            #pragma unroll
            for (int i = 0; i < 8; i++) z[i] = (_Float16)0;
            a_x[kt] = z;
        }
    }

    f32x4 acc[24];
    #pragma unroll
    for (int nt = 0; nt < 24; nt++)
        #pragma unroll
        for (int q = 0; q < 4; q++) acc[nt][q] = 0.f;

    #pragma unroll
    for (int kt = 0; kt < 2; kt++) {
        #pragma unroll
        for (int nt = 0; nt < 24; nt++) {
            f16x8 b = *(const f16x8*)(wlds + (kt * 24 + nt) * 512 + m * 32 + quad * 8);
            acc[nt] = __builtin_amdgcn_mfma_f32_16x16x32_f16(
                (nt < 12) ? a_agg[kt] : a_x[kt], b, acc[nt], 0, 0, 0);
        }
    }

    // epilogue: node = quad*4 + r (C row), h = t*16 + m (C col)
    #pragma unroll
    for (int t = 0; t < 4; t++) {
        const int h = t * 16 + m;
        const float bir = bih[h], biz = bih[64 + h], bin = bih[128 + h];
        const float bhr = bhh[h], bhz = bhh[64 + h], bhn = bhh[128 + h];
        #pragma unroll
        for (int r = 0; r < 4; r++) {
            const int nd = nbase + quad * 4 + r;
            if (nd >= NN) continue;
            float ir  = acc[t][r]      + bir;
            float iz  = acc[4 + t][r]  + biz;
            float in_ = acc[8 + t][r]  + bin;
            float hr  = acc[12 + t][r] + bhr;
            float hz  = acc[16 + t][r] + bhz;
            float hn  = acc[20 + t][r] + bhn;
            float rg = sigm(ir + hr);
            float z  = sigm(iz + hz);
            float n  = tanh_fast(in_ + rg * hn);
            float xold = x[(size_t)nd * 64 + h];
            float xn = (1.0f - z) * n + z * xold;
            x[(size_t)nd * 64 + h] = xn;
            xh[(size_t)nd * 64 + h] = __float2half(xn);
        }
    }
}

// out[n] = x[n].Wout + bout; pooled[batch[n]] += out[n]
__global__ __launch_bounds__(256) void pool_kernel(
    const float* __restrict__ x, const float* __restrict__ Wout,
    const float* __restrict__ bout, const int* __restrict__ batch,
    float* __restrict__ out)
{
    const int node = blockIdx.x * 256 + threadIdx.x;
    if (node >= NN) return;
    float acc = bout[0];
    const float4* xp = (const float4*)(x + (size_t)node * 64);
    #pragma unroll
    for (int i = 0; i < 16; i++) {
        float4 v = xp[i];
        acc += v.x * Wout[4*i] + v.y * Wout[4*i+1] + v.z * Wout[4*i+2] + v.w * Wout[4*i+3];
    }
    atomicAdd(out + batch[node], acc);
}

extern "C" void kernel_launch(void* const* d_in, const int* in_sizes, int n_in,
                              void* d_out, int out_size, void* d_ws, size_t ws_size,
                              hipStream_t stream)
{
    const float* nf   = (const float*)d_in[0];
    const float* ef   = (const float*)d_in[1];
    const int*   Esrc = (const int*)  d_in[2];
    const int*   Etgt = (const int*)  d_in[3];
    const int*   bat  = (const int*)  d_in[4];
    const float* Win  = (const float*)d_in[5];
    const float* bin_ = (const float*)d_in[6];
    const float* We1  = (const float*)d_in[7];
    const float* be1  = (const float*)d_in[8];
    const float* We2  = (const float*)d_in[9];
    const float* be2  = (const float*)d_in[10];
    const float* Wih  = (const float*)d_in[11];
    const float* bih  = (const float*)d_in[12];
    const float* Whh  = (const float*)d_in[13];
    const float* bhh  = (const float*)d_in[14];
    const float* Wout = (const float*)d_in[15];
    const float* bout = (const float*)d_in[16];

    char* ws = (char*)d_ws;
    float*  x          = (float*)(ws);                // 12,800,000 B
    float*  msgf       = (float*)(ws + 12800000);     // 25,600,000 B
    __half* xh         = (__half*)(ws + 38400000);    //  6,400,000 B
    __half* ehh        = (__half*)(ws + 44800000);    // 12,800,000 B
    __half* Bp         = (__half*)(ws + 57600000);    //    532,480 B
    __half* WG         = (__half*)(ws + 58132480);    //     49,152 B
    int*    cnt        = (int*)   (ws + 58181632);    //    200,016 B
    int*    off        = (int*)   (ws + 58381648);    //    200,016 B
    int*    wpos       = (int*)   (ws + 58581664);    //    200,016 B
    int*    inv        = (int*)   (ws + 58781680);    //    400,000 B
    int*    tgt_sorted = (int*)   (ws + 59181680);    //    400,000 B
    int*    bsum       = (int*)   (ws + 59581680);    //      1,024 B
    int*    bscan      = (int*)   (ws + 59582704);    //      1,024 B

    hipMemsetAsync(d_out, 0, NB * sizeof(float), stream);
    hipMemsetAsync(cnt, 0, (NN + 1) * sizeof(int), stream);

    node_in_kernel<<<(NN * 64 + 255) / 256, 256, 0, stream>>>(nf, Win, bin_, x, xh);
    edge_l1_kernel<<<(NE * 64 + 255) / 256, 256, 0, stream>>>(ef, We1, be1, ehh);
    pack_b_kernel<<<(130 * 2048 + 255) / 256, 256, 0, stream>>>(We2, be2, Bp);
    pack_gru_kernel<<<(24576 + 255) / 256, 256, 0, stream>>>(Wih, Whh, WG);

    hist_kernel<<<(NE + 255) / 256, 256, 0, stream>>>(Etgt, cnt);
    scanA_kernel<<<NBLK_SCAN, 256, 0, stream>>>(cnt, bsum);
    scanB_kernel<<<1, 256, 0, stream>>>(bsum, bscan, off);
    scanC_kernel<<<NBLK_SCAN, 256, 0, stream>>>(cnt, bscan, off, wpos);
    scatter_kernel<<<(NE + 255) / 256, 256, 0, stream>>>(Etgt, wpos, inv, tgt_sorted);

    for (int t = 0; t < 3; t++) {
        msg_kernel<<<(NE + 127) / 128, 256, 0, stream>>>(xh, ehh, Bp, Esrc, inv, msgf);
        gru_kernel<<<(NN + 63) / 64, 256, 0, stream>>>(msgf, off, tgt_sorted, x, xh, WG, bih, bhh);
    }

    pool_kernel<<<(NN + 255) / 256, 256, 0, stream>>>(x, Wout, bout, bat, (float*)d_out);
}

// Round 6
// 568.234 us; speedup vs baseline: 1.1092x; 1.0421x over previous
//
#include <hip/hip_runtime.h>
#include <hip/hip_fp16.h>

#define NN 50000   // nodes
#define NE 100000  // edges
#define NB 512     // graphs
#define NBLK_SCAN 196   // ceil(NN/256)
// H = 64, F_NODE = 16, F_EDGE = 8, T = 3

typedef _Float16 f16x8 __attribute__((ext_vector_type(8)));
typedef float f32x4   __attribute__((ext_vector_type(4)));
typedef float f32x16  __attribute__((ext_vector_type(16)));

__device__ __forceinline__ float sigm(float v) { return 1.0f / (1.0f + __expf(-v)); }
__device__ __forceinline__ float tanh_fast(float v) {
    float e = __expf(-2.0f * fabsf(v));
    float t = (1.0f - e) / (1.0f + e);
    return v < 0.f ? -t : t;
}

// ---- fused prep kernel: node_in ++ edge_l1 ++ pack_b(32x32) ++ pack_gru ----
// block ranges: [0,12500) node_in, [12500,37500) edge_l1,
//               [37500,38540) pack_b, [38540,38636) pack_gru
#define PREP_GRID 38636

__global__ __launch_bounds__(256) void prep_kernel(
    const float* __restrict__ nf, const float* __restrict__ Win,
    const float* __restrict__ bin_, float* __restrict__ x, __half* __restrict__ xh,
    const float* __restrict__ ef, const float* __restrict__ We1,
    const float* __restrict__ be1, __half* __restrict__ ehh,
    const float* __restrict__ We2, const float* __restrict__ be2,
    __half* __restrict__ Bp,
    const float* __restrict__ Wih, const float* __restrict__ Whh,
    __half* __restrict__ WG)
{
    const int b = blockIdx.x;
    const int tid = threadIdx.x;
    if (b < 12500) {
        // x[n][h] = node_features[n].Win[h] + bin[h]; + f16 copy
        int idx = b * 256 + tid;
        int n = idx >> 6, h = idx & 63;
        float acc = bin_[h];
        #pragma unroll
        for (int f = 0; f < 16; f++) acc += nf[n * 16 + f] * Win[h * 16 + f];
        x[idx] = acc;
        xh[idx] = __float2half(acc);
    } else if (b < 37500) {
        // ehh[e][k] = f16(relu(edge_features[e].We1[k] + be1[k]))
        int idx = (b - 12500) * 256 + tid;
        int e = idx >> 6, k = idx & 63;
        float acc = be1[k];
        #pragma unroll
        for (int f = 0; f < 8; f++) acc += ef[e * 8 + f] * We1[k * 8 + f];
        ehh[idx] = __float2half(fmaxf(acc, 0.0f));
    } else if (b < 38540) {
        // Pack We2 (+be2 K-ext) into 32x32x16 lane-linear B-frag order:
        // Bp[kt*1024 + nt*512 + lane*8 + ii]; n = nt*32 + (lane&31);
        // p = kt*16 + (lane>>5)*8 + ii (contraction idx, 0..4159);
        // p<4096: We2[(n*64 + p>>6)*64 + (p&63)], else be2[n*64 + (p-4096)]
        int idx = (b - 37500) * 256 + tid;    // 0 .. 266239 (260 kt x 1024)
        int ii = idx & 7;
        int l  = (idx >> 3) & 63;
        int nt = (idx >> 9) & 1;
        int kt = idx >> 10;
        int n  = nt * 32 + (l & 31);
        int p  = kt * 16 + ((l >> 5) << 3) + ii;
        float v;
        if (p < 4096) {
            v = We2[((size_t)(n * 64 + (p >> 6))) * 64 + (p & 63)];
        } else {
            v = be2[n * 64 + (p - 4096)];
        }
        Bp[idx] = __float2half(v);
    } else {
        // Pack GRU weights, 16x16x32 B-frag layout WG[kt][nt][n][kk]
        int idx = (b - 38540) * 256 + tid;    // 0 .. 24575
        int kk = idx & 31;
        int n  = (idx >> 5) & 15;
        int nt = (idx >> 9) % 24;
        int kt = (idx >> 9) / 24;
        int k = kt * 32 + kk;
        int col192 = (nt % 12) * 16 + n;
        int gate = col192 >> 6, h = col192 & 63;
        const float* src = (nt < 12) ? Wih : Whh;
        WG[idx] = __float2half(src[((size_t)(gate * 64 + h)) * 64 + k]);
    }
}

// ---- counting sort of edges by target ----

__global__ __launch_bounds__(256) void hist_kernel(
    const int* __restrict__ Etgt, int* __restrict__ cnt)
{
    int e = blockIdx.x * 256 + threadIdx.x;
    if (e < NE) atomicAdd(&cnt[Etgt[e]], 1);
}

__device__ __forceinline__ int block_excl_scan(int v, int tid, int* lds)
{
    int lane = tid & 63, w = tid >> 6;
    int incl = v;
    #pragma unroll
    for (int d = 1; d < 64; d <<= 1) {
        int u = __shfl_up(incl, d, 64);
        if (lane >= d) incl += u;
    }
    if (lane == 63) lds[w] = incl;
    __syncthreads();
    if (tid == 0) {
        int a = lds[0], b = lds[1], c = lds[2];
        lds[4] = 0; lds[5] = a; lds[6] = a + b; lds[7] = a + b + c;
    }
    __syncthreads();
    return incl - v + lds[4 + w];
}

__global__ __launch_bounds__(256) void scanA_kernel(
    const int* __restrict__ cnt, int* __restrict__ bsum)
{
    __shared__ int s4[4];
    int tid = threadIdx.x;
    int idx = blockIdx.x * 256 + tid;
    int v = (idx < NN) ? cnt[idx] : 0;
    #pragma unroll
    for (int d = 1; d < 64; d <<= 1) v += __shfl_xor(v, d, 64);
    if ((tid & 63) == 0) s4[tid >> 6] = v;
    __syncthreads();
    if (tid == 0) bsum[blockIdx.x] = s4[0] + s4[1] + s4[2] + s4[3];
}

__global__ __launch_bounds__(256) void scanB_kernel(
    const int* __restrict__ bsum, int* __restrict__ bscan, int* __restrict__ off)
{
    __shared__ int lds[8];
    int tid = threadIdx.x;
    int v = (tid < NBLK_SCAN) ? bsum[tid] : 0;
    int ex = block_excl_scan(v, tid, lds);
    if (tid < NBLK_SCAN) bscan[tid] = ex;
    if (tid == NBLK_SCAN) off[NN] = ex;   // total
}

__global__ __launch_bounds__(256) void scanC_kernel(
    const int* __restrict__ cnt, const int* __restrict__ bscan,
    int* __restrict__ off, int* __restrict__ wpos)
{
    __shared__ int lds[8];
    int tid = threadIdx.x;
    int idx = blockIdx.x * 256 + tid;
    int v = (idx < NN) ? cnt[idx] : 0;
    int ex = block_excl_scan(v, tid, lds) + bscan[blockIdx.x];
    if (idx < NN) { off[idx] = ex; wpos[idx] = ex; }
}

__global__ __launch_bounds__(256) void scatter_kernel(
    const int* __restrict__ Etgt, int* __restrict__ wpos,
    int* __restrict__ inv, int* __restrict__ tgt_sorted)
{
    int e = blockIdx.x * 256 + threadIdx.x;
    if (e < NE) {
        int t = Etgt[e];
        int p = atomicAdd(&wpos[t], 1);
        inv[e] = p;
        tgt_sorted[p] = t;
    }
}

// Fused message GEMM: msg[e][i] = sum_{j,k} We2[i*64+j][k]*x[src][j]*eh[e][k] (+be2)
// v6: 32x32x16 MFMA (half the MFMA instrs at better rate), R3 occupancy point:
// 4 waves x 32 edges = 128 edges/block, 35.3KB LDS -> 4 blocks/CU, grid 782
// single-round. B reg-staged double-buffer, 1 barrier/j. No atomics.
__global__ __launch_bounds__(256, 4) void msg_kernel(
    const __half* __restrict__ xh, const __half* __restrict__ ehh,
    const __half* __restrict__ Bp,
    const int* __restrict__ Esrc, const int* __restrict__ inv,
    float* __restrict__ msgf)
{
    __shared__ __align__(16) __half xs[128][72];     // 18432 B
    __shared__ __align__(16) __half bbuf[2][4096];   // 16384 B (one 8KB j-tile each)
    __shared__ int inv_s[128];
    const int tid = threadIdx.x;
    const int e0 = blockIdx.x * 128;
    const int w = tid >> 6, lane = tid & 63;
    const int l31 = lane & 31, khalf = lane >> 5;

    {   // stage gathered f16 source rows: 128 rows, 2 threads per row (64B each)
        const int r = tid >> 1, part = tid & 1;
        const int e = e0 + r;
        const bool ok = (e < NE);
        const int src = ok ? Esrc[e] : 0;
        if (part == 0) inv_s[r] = ok ? inv[e] : 0;
        const uint4* xsrc = (const uint4*)(xh + (size_t)src * 64 + part * 32);
        __half* dst = &xs[r][part * 32];
        #pragma unroll
        for (int i = 0; i < 4; i++) {
            uint4 v = ok ? xsrc[i] : make_uint4(0, 0, 0, 0);
            *(uint4*)(dst + i * 8) = v;
        }
    }

    {   // prologue: B tile j=0 -> bbuf[0]; tid-linear, conflict-free
        const uint4* s = (const uint4*)Bp;
        uint4 v0 = s[tid], v1 = s[256 + tid];
        ((uint4*)bbuf[0])[tid] = v0;
        ((uint4*)bbuf[0])[256 + tid] = v1;
    }

    // per-lane eh cache: this lane's edge, 4 kt16-chunks of 8 halves
    // (k = kt*16 + khalf*8 + ii)
    const int eMine = e0 + w * 32 + l31;
    __half2 ehc2[4][4];
    if (eMine < NE) {
        #pragma unroll
        for (int kt = 0; kt < 4; kt++) {
            union { uint4 u; __half2 h[4]; } u0;
            u0.u = *(const uint4*)(ehh + (size_t)eMine * 64 + kt * 16 + khalf * 8);
            #pragma unroll
            for (int q = 0; q < 4; q++) ehc2[kt][q] = u0.h[q];
        }
    } else {
        __half2 z = __halves2half2(__float2half(0.f), __float2half(0.f));
        #pragma unroll
        for (int kt = 0; kt < 4; kt++)
            #pragma unroll
            for (int q = 0; q < 4; q++) ehc2[kt][q] = z;
    }

    f32x16 acc[2];
    #pragma unroll
    for (int nt = 0; nt < 2; nt++)
        #pragma unroll
        for (int q = 0; q < 16; q++) acc[nt][q] = 0.f;

    __syncthreads();   // xs + bbuf[0] ready

    int cur = 0;
    #pragma unroll 1
    for (int j = 0; j < 64; j++) {
        // prefetch next j-tile (j=63 -> be2 tail tile at halves 64*4096)
        const uint4* s = (const uint4*)(Bp + (size_t)(j + 1) * 4096);
        uint4 p0 = s[tid];
        uint4 p1 = s[256 + tid];

        const __half xv = xs[w * 32 + l31][j];
        const __half2 xb = __half2half2(xv);

        #pragma unroll
        for (int kt = 0; kt < 4; kt++) {
            union { __half2 h[4]; f16x8 v; } u;
            #pragma unroll
            for (int q = 0; q < 4; q++) u.h[q] = __hmul2(xb, ehc2[kt][q]);
            #pragma unroll
            for (int nt = 0; nt < 2; nt++) {
                f16x8 bf = *(const f16x8*)(&bbuf[cur][(kt * 2 + nt) * 512 + lane * 8]);
                acc[nt] = __builtin_amdgcn_mfma_f32_32x32x16_f16(
                    u.v, bf, acc[nt], 0, 0, 0);
            }
        }

        uint4* d = (uint4*)bbuf[cur ^ 1];
        d[tid] = p0;
        d[256 + tid] = p1;
        __syncthreads();
        cur ^= 1;
    }

    // be2 K-extension (kt16 256..259, staged in bbuf[cur]): A = xs row chunk
    #pragma unroll
    for (int ktl = 0; ktl < 4; ktl++) {
        f16x8 af = *(const f16x8*)(&xs[w * 32 + l31][ktl * 16 + khalf * 8]);
        #pragma unroll
        for (int nt = 0; nt < 2; nt++) {
            f16x8 bf = *(const f16x8*)(&bbuf[cur][(ktl * 2 + nt) * 512 + lane * 8]);
            acc[nt] = __builtin_amdgcn_mfma_f32_32x32x16_f16(
                af, bf, acc[nt], 0, 0, 0);
        }
    }

    // C layout (32x32): col i = lane&31, row = (r&3)+8*(r>>2)+4*(lane>>5)
    #pragma unroll
    for (int nt = 0; nt < 2; nt++) {
        #pragma unroll
        for (int r = 0; r < 16; r++) {
            const int erow = w * 32 + (r & 3) + 8 * (r >> 2) + 4 * khalf;
            const int e = e0 + erow;
            if (e < NE)
                msgf[(size_t)inv_s[erow] * 64 + nt * 32 + l31] = acc[nt][r];
        }
    }
}

// GRU via MFMA, v5: no wlds (B-frags direct from L2-hot WG), per-t-group acc
// (6 live accs) -> LDS 17.4KB, 4 blocks/CU, grid 782 single-round.
// Fused pool epilogue on the last step (dopool).
__global__ __launch_bounds__(256, 4) void gru_kernel(
    const float* __restrict__ msgf, const int* __restrict__ off,
    const int* __restrict__ tgt_sorted,
    float* __restrict__ x, __half* __restrict__ xh,
    const __half* __restrict__ WG,
    const float* __restrict__ bih, const float* __restrict__ bhh,
    const float* __restrict__ Wout, const float* __restrict__ bout,
    const int* __restrict__ batch, float* __restrict__ out, int dopool)
{
    __shared__ float aggs[64][68];   // 17.4 KB
    const int tid = threadIdx.x;
    const int w = tid >> 6, lane = tid & 63, m = lane & 15, quad = lane >> 4;
    const int nb0 = blockIdx.x * 64;

    {   // zero aggs (64*68 = 4352 floats = 17 per thread)
        float* a = &aggs[0][0];
        #pragma unroll
        for (int i = 0; i < 17; i++) a[i * 256 + tid] = 0.f;
    }
    __syncthreads();

    const int hi = (nb0 + 64 < NN) ? nb0 + 64 : NN;
    {   // row-parallel segment-sum over contiguous sorted rows
        const int r0 = off[nb0], r1 = off[hi];
        for (int p = r0 + w; p < r1; p += 4) {
            float v = msgf[(size_t)p * 64 + lane];
            int t = tgt_sorted[p];
            atomicAdd(&aggs[t - nb0][lane], v);
        }
    }
    __syncthreads();

    const int nbase = nb0 + w * 16;
    const int anode = nbase + m;
    const bool aok = (anode < NN);

    f16x8 a_agg[2], a_x[2];
    #pragma unroll
    for (int kt = 0; kt < 2; kt++) {
        const int koff = kt * 32 + quad * 8;
        {
            const float* ap = &aggs[w * 16 + m][koff];
            float4 f0 = *(const float4*)ap;
            float4 f1 = *(const float4*)(ap + 4);
            union { __half2 h[4]; f16x8 v; } u;
            u.h[0] = __floats2half2_rn(f0.x, f0.y);
            u.h[1] = __floats2half2_rn(f0.z, f0.w);
            u.h[2] = __floats2half2_rn(f1.x, f1.y);
            u.h[3] = __floats2half2_rn(f1.z, f1.w);
            a_agg[kt] = u.v;
        }
        if (aok) {
            a_x[kt] = *(const f16x8*)(xh + (size_t)anode * 64 + koff);
        } else {
            f16x8 z;
            #pragma unroll
            for (int i = 0; i < 8; i++) z[i] = (_Float16)0;
            a_x[kt] = z;
        }
    }

    float pdr0 = 0.f, pdr1 = 0.f, pdr2 = 0.f, pdr3 = 0.f;

    #pragma unroll
    for (int t = 0; t < 4; t++) {
        // gates for columns h = t*16 + m live in nt = g*4 + t, g = 0..5
        f32x4 accg[6];
        #pragma unroll
        for (int g = 0; g < 6; g++)
            #pragma unroll
            for (int q = 0; q < 4; q++) accg[g][q] = 0.f;

        #pragma unroll
        for (int g = 0; g < 6; g++) {
            const int nt = g * 4 + t;
            #pragma unroll
            for (int kt = 0; kt < 2; kt++) {
                f16x8 b = *(const f16x8*)(WG + (size_t)(kt * 24 + nt) * 512 + m * 32 + quad * 8);
                accg[g] = __builtin_amdgcn_mfma_f32_16x16x32_f16(
                    (g < 3) ? a_agg[kt] : a_x[kt], b, accg[g], 0, 0, 0);
            }
        }

        const int h = t * 16 + m;
        const float bir = bih[h], biz = bih[64 + h], bin = bih[128 + h];
        const float bhr = bhh[h], bhz = bhh[64 + h], bhn = bhh[128 + h];
        const float wo = dopool ? Wout[h] : 0.f;
        #pragma unroll
        for (int r = 0; r < 4; r++) {
            const int nd = nbase + quad * 4 + r;
            if (nd >= NN) continue;
            float ir  = accg[0][r] + bir;
            float iz  = accg[1][r] + biz;
            float in_ = accg[2][r] + bin;
            float hr  = accg[3][r] + bhr;
            float hz  = accg[4][r] + bhz;
            float hn  = accg[5][r] + bhn;
            float rg = sigm(ir + hr);
            float z  = sigm(iz + hz);
            float n  = tanh_fast(in_ + rg * hn);
            float xold = x[(size_t)nd * 64 + h];
            float xn = (1.0f - z) * n + z * xold;
            x[(size_t)nd * 64 + h] = xn;
            xh[(size_t)nd * 64 + h] = __float2half(xn);
            float c = xn * wo;
            if (r == 0) pdr0 += c; else if (r == 1) pdr1 += c;
            else if (r == 2) pdr2 += c; else pdr3 += c;
        }
    }

    if (dopool) {
        float pdr[4] = {pdr0, pdr1, pdr2, pdr3};
        #pragma unroll
        for (int r = 0; r < 4; r++) {
            float v = pdr[r];
            v += __shfl_xor(v, 1, 16);
            v += __shfl_xor(v, 2, 16);
            v += __shfl_xor(v, 4, 16);
            v += __shfl_xor(v, 8, 16);
            if (m == 0) {
                const int nd = nbase + quad * 4 + r;
                if (nd < NN) atomicAdd(out + batch[nd], v + bout[0]);
            }
        }
    }
}

extern "C" void kernel_launch(void* const* d_in, const int* in_sizes, int n_in,
                              void* d_out, int out_size, void* d_ws, size_t ws_size,
                              hipStream_t stream)
{
    const float* nf   = (const float*)d_in[0];
    const float* ef   = (const float*)d_in[1];
    const int*   Esrc = (const int*)  d_in[2];
    const int*   Etgt = (const int*)  d_in[3];
    const int*   bat  = (const int*)  d_in[4];
    const float* Win  = (const float*)d_in[5];
    const float* bin_ = (const float*)d_in[6];
    const float* We1  = (const float*)d_in[7];
    const float* be1  = (const float*)d_in[8];
    const float* We2  = (const float*)d_in[9];
    const float* be2  = (const float*)d_in[10];
    const float* Wih  = (const float*)d_in[11];
    const float* bih  = (const float*)d_in[12];
    const float* Whh  = (const float*)d_in[13];
    const float* bhh  = (const float*)d_in[14];
    const float* Wout = (const float*)d_in[15];
    const float* bout = (const float*)d_in[16];

    char* ws = (char*)d_ws;
    float*  x          = (float*)(ws);                // 12,800,000 B
    float*  msgf       = (float*)(ws + 12800000);     // 25,600,000 B
    __half* xh         = (__half*)(ws + 38400000);    //  6,400,000 B
    __half* ehh        = (__half*)(ws + 44800000);    // 12,800,000 B
    __half* Bp         = (__half*)(ws + 57600000);    //    532,480 B
    __half* WG         = (__half*)(ws + 58132480);    //     49,152 B
    int*    cnt        = (int*)   (ws + 58181632);    //    200,016 B
    int*    off        = (int*)   (ws + 58381648);    //    200,016 B
    int*    wpos       = (int*)   (ws + 58581664);    //    200,016 B
    int*    inv        = (int*)   (ws + 58781680);    //    400,000 B
    int*    tgt_sorted = (int*)   (ws + 59181680);    //    400,000 B
    int*    bsum       = (int*)   (ws + 59581680);    //      1,024 B
    int*    bscan      = (int*)   (ws + 59582704);    //      1,024 B

    hipMemsetAsync(d_out, 0, NB * sizeof(float), stream);
    hipMemsetAsync(cnt, 0, (NN + 1) * sizeof(int), stream);

    prep_kernel<<<PREP_GRID, 256, 0, stream>>>(
        nf, Win, bin_, x, xh, ef, We1, be1, ehh, We2, be2, Bp, Wih, Whh, WG);

    hist_kernel<<<(NE + 255) / 256, 256, 0, stream>>>(Etgt, cnt);
    scanA_kernel<<<NBLK_SCAN, 256, 0, stream>>>(cnt, bsum);
    scanB_kernel<<<1, 256, 0, stream>>>(bsum, bscan, off);
    scanC_kernel<<<NBLK_SCAN, 256, 0, stream>>>(cnt, bscan, off, wpos);
    scatter_kernel<<<(NE + 255) / 256, 256, 0, stream>>>(Etgt, wpos, inv, tgt_sorted);

    for (int t = 0; t < 3; t++) {
        msg_kernel<<<(NE + 127) / 128, 256, 0, stream>>>(xh, ehh, Bp, Esrc, inv, msgf);
        gru_kernel<<<(NN + 63) / 64, 256, 0, stream>>>(
            msgf, off, tgt_sorted, x, xh, WG, bih, bhh,
            Wout, bout, bat, (float*)d_out, (t == 2) ? 1 : 0);
    }
}

// Round 7
// 540.131 us; speedup vs baseline: 1.1669x; 1.0520x over previous
//
#include <hip/hip_runtime.h>
#include <hip/hip_fp16.h>

#define NN 50000   // nodes
#define NE 100000  // edges
#define NB 512     // graphs
#define NBLK_SCAN 196   // ceil(NN/256)
// H = 64, F_NODE = 16, F_EDGE = 8, T = 3

typedef _Float16 f16x8 __attribute__((ext_vector_type(8)));
typedef float f32x4   __attribute__((ext_vector_type(4)));
typedef float f32x16  __attribute__((ext_vector_type(16)));

__device__ __forceinline__ float sigm(float v) { return 1.0f / (1.0f + __expf(-v)); }
__device__ __forceinline__ float tanh_fast(float v) {
    float e = __expf(-2.0f * fabsf(v));
    float t = (1.0f - e) / (1.0f + e);
    return v < 0.f ? -t : t;
}

// ---- fused prep kernel: node_in ++ edge_l1 ++ pack_b(32x32) ++ pack_gru ----
#define PREP_GRID 38636

__global__ __launch_bounds__(256) void prep_kernel(
    const float* __restrict__ nf, const float* __restrict__ Win,
    const float* __restrict__ bin_, float* __restrict__ x, __half* __restrict__ xh,
    const float* __restrict__ ef, const float* __restrict__ We1,
    const float* __restrict__ be1, __half* __restrict__ ehh,
    const float* __restrict__ We2, const float* __restrict__ be2,
    __half* __restrict__ Bp,
    const float* __restrict__ Wih, const float* __restrict__ Whh,
    __half* __restrict__ WG)
{
    const int b = blockIdx.x;
    const int tid = threadIdx.x;
    if (b < 12500) {
        int idx = b * 256 + tid;
        int n = idx >> 6, h = idx & 63;
        float acc = bin_[h];
        #pragma unroll
        for (int f = 0; f < 16; f++) acc += nf[n * 16 + f] * Win[h * 16 + f];
        x[idx] = acc;
        xh[idx] = __float2half(acc);
    } else if (b < 37500) {
        int idx = (b - 12500) * 256 + tid;
        int e = idx >> 6, k = idx & 63;
        float acc = be1[k];
        #pragma unroll
        for (int f = 0; f < 8; f++) acc += ef[e * 8 + f] * We1[k * 8 + f];
        ehh[idx] = __float2half(fmaxf(acc, 0.0f));
    } else if (b < 38540) {
        // Pack We2 (+be2 K-ext) into 32x32x16 lane-linear B-frag order
        int idx = (b - 37500) * 256 + tid;    // 0 .. 266239 (260 kt x 1024)
        int ii = idx & 7;
        int l  = (idx >> 3) & 63;
        int nt = (idx >> 9) & 1;
        int kt = idx >> 10;
        int n  = nt * 32 + (l & 31);
        int p  = kt * 16 + ((l >> 5) << 3) + ii;
        float v;
        if (p < 4096) {
            v = We2[((size_t)(n * 64 + (p >> 6))) * 64 + (p & 63)];
        } else {
            v = be2[n * 64 + (p - 4096)];
        }
        Bp[idx] = __float2half(v);
    } else {
        // Pack GRU weights, 16x16x32 B-frag layout WG[kt][nt][n][kk]
        int idx = (b - 38540) * 256 + tid;    // 0 .. 24575
        int kk = idx & 31;
        int n  = (idx >> 5) & 15;
        int nt = (idx >> 9) % 24;
        int kt = (idx >> 9) / 24;
        int k = kt * 32 + kk;
        int col192 = (nt % 12) * 16 + n;
        int gate = col192 >> 6, h = col192 & 63;
        const float* src = (nt < 12) ? Wih : Whh;
        WG[idx] = __float2half(src[((size_t)(gate * 64 + h)) * 64 + k]);
    }
}

// ---- counting sort of edges by target ----

__global__ __launch_bounds__(256) void hist_kernel(
    const int* __restrict__ Etgt, int* __restrict__ cnt)
{
    int e = blockIdx.x * 256 + threadIdx.x;
    if (e < NE) atomicAdd(&cnt[Etgt[e]], 1);
}

__device__ __forceinline__ int block_excl_scan(int v, int tid, int* lds)
{
    int lane = tid & 63, w = tid >> 6;
    int incl = v;
    #pragma unroll
    for (int d = 1; d < 64; d <<= 1) {
        int u = __shfl_up(incl, d, 64);
        if (lane >= d) incl += u;
    }
    if (lane == 63) lds[w] = incl;
    __syncthreads();
    if (tid == 0) {
        int a = lds[0], b = lds[1], c = lds[2];
        lds[4] = 0; lds[5] = a; lds[6] = a + b; lds[7] = a + b + c;
    }
    __syncthreads();
    return incl - v + lds[4 + w];
}

__global__ __launch_bounds__(256) void scanA_kernel(
    const int* __restrict__ cnt, int* __restrict__ bsum)
{
    __shared__ int s4[4];
    int tid = threadIdx.x;
    int idx = blockIdx.x * 256 + tid;
    int v = (idx < NN) ? cnt[idx] : 0;
    #pragma unroll
    for (int d = 1; d < 64; d <<= 1) v += __shfl_xor(v, d, 64);
    if ((tid & 63) == 0) s4[tid >> 6] = v;
    __syncthreads();
    if (tid == 0) bsum[blockIdx.x] = s4[0] + s4[1] + s4[2] + s4[3];
}

__global__ __launch_bounds__(256) void scanB_kernel(
    const int* __restrict__ bsum, int* __restrict__ bscan, int* __restrict__ off)
{
    __shared__ int lds[8];
    int tid = threadIdx.x;
    int v = (tid < NBLK_SCAN) ? bsum[tid] : 0;
    int ex = block_excl_scan(v, tid, lds);
    if (tid < NBLK_SCAN) bscan[tid] = ex;
    if (tid == NBLK_SCAN) off[NN] = ex;   // total
}

__global__ __launch_bounds__(256) void scanC_kernel(
    const int* __restrict__ cnt, const int* __restrict__ bscan,
    int* __restrict__ off, int* __restrict__ wpos)
{
    __shared__ int lds[8];
    int tid = threadIdx.x;
    int idx = blockIdx.x * 256 + tid;
    int v = (idx < NN) ? cnt[idx] : 0;
    int ex = block_excl_scan(v, tid, lds) + bscan[blockIdx.x];
    if (idx < NN) { off[idx] = ex; wpos[idx] = ex; }
}

__global__ __launch_bounds__(256) void scatter_kernel(
    const int* __restrict__ Etgt, int* __restrict__ wpos,
    int* __restrict__ inv, int* __restrict__ tgt_sorted)
{
    int e = blockIdx.x * 256 + threadIdx.x;
    if (e < NE) {
        int t = Etgt[e];
        int p = atomicAdd(&wpos[t], 1);
        inv[e] = p;
        tgt_sorted[p] = t;
    }
}

// Fused message GEMM (unchanged from R6): 32x32x16 MFMA, 128 edges/block,
// 35.3KB LDS -> 4 blocks/CU, grid 782 single-round. No atomics.
__global__ __launch_bounds__(256, 4) void msg_kernel(
    const __half* __restrict__ xh, const __half* __restrict__ ehh,
    const __half* __restrict__ Bp,
    const int* __restrict__ Esrc, const int* __restrict__ inv,
    float* __restrict__ msgf)
{
    __shared__ __align__(16) __half xs[128][72];     // 18432 B
    __shared__ __align__(16) __half bbuf[2][4096];   // 16384 B
    __shared__ int inv_s[128];
    const int tid = threadIdx.x;
    const int e0 = blockIdx.x * 128;
    const int w = tid >> 6, lane = tid & 63;
    const int l31 = lane & 31, khalf = lane >> 5;

    {   // stage gathered f16 source rows: 128 rows, 2 threads per row (64B each)
        const int r = tid >> 1, part = tid & 1;
        const int e = e0 + r;
        const bool ok = (e < NE);
        const int src = ok ? Esrc[e] : 0;
        if (part == 0) inv_s[r] = ok ? inv[e] : 0;
        const uint4* xsrc = (const uint4*)(xh + (size_t)src * 64 + part * 32);
        __half* dst = &xs[r][part * 32];
        #pragma unroll
        for (int i = 0; i < 4; i++) {
            uint4 v = ok ? xsrc[i] : make_uint4(0, 0, 0, 0);
            *(uint4*)(dst + i * 8) = v;
        }
    }

    {   // prologue: B tile j=0 -> bbuf[0]
        const uint4* s = (const uint4*)Bp;
        uint4 v0 = s[tid], v1 = s[256 + tid];
        ((uint4*)bbuf[0])[tid] = v0;
        ((uint4*)bbuf[0])[256 + tid] = v1;
    }

    const int eMine = e0 + w * 32 + l31;
    __half2 ehc2[4][4];
    if (eMine < NE) {
        #pragma unroll
        for (int kt = 0; kt < 4; kt++) {
            union { uint4 u; __half2 h[4]; } u0;
            u0.u = *(const uint4*)(ehh + (size_t)eMine * 64 + kt * 16 + khalf * 8);
            #pragma unroll
            for (int q = 0; q < 4; q++) ehc2[kt][q] = u0.h[q];
        }
    } else {
        __half2 z = __halves2half2(__float2half(0.f), __float2half(0.f));
        #pragma unroll
        for (int kt = 0; kt < 4; kt++)
            #pragma unroll
            for (int q = 0; q < 4; q++) ehc2[kt][q] = z;
    }

    f32x16 acc[2];
    #pragma unroll
    for (int nt = 0; nt < 2; nt++)
        #pragma unroll
        for (int q = 0; q < 16; q++) acc[nt][q] = 0.f;

    __syncthreads();

    int cur = 0;
    #pragma unroll 1
    for (int j = 0; j < 64; j++) {
        const uint4* s = (const uint4*)(Bp + (size_t)(j + 1) * 4096);
        uint4 p0 = s[tid];
        uint4 p1 = s[256 + tid];

        const __half xv = xs[w * 32 + l31][j];
        const __half2 xb = __half2half2(xv);

        #pragma unroll
        for (int kt = 0; kt < 4; kt++) {
            union { __half2 h[4]; f16x8 v; } u;
            #pragma unroll
            for (int q = 0; q < 4; q++) u.h[q] = __hmul2(xb, ehc2[kt][q]);
            #pragma unroll
            for (int nt = 0; nt < 2; nt++) {
                f16x8 bf = *(const f16x8*)(&bbuf[cur][(kt * 2 + nt) * 512 + lane * 8]);
                acc[nt] = __builtin_amdgcn_mfma_f32_32x32x16_f16(
                    u.v, bf, acc[nt], 0, 0, 0);
            }
        }

        uint4* d = (uint4*)bbuf[cur ^ 1];
        d[tid] = p0;
        d[256 + tid] = p1;
        __syncthreads();
        cur ^= 1;
    }

    // be2 K-extension
    #pragma unroll
    for (int ktl = 0; ktl < 4; ktl++) {
        f16x8 af = *(const f16x8*)(&xs[w * 32 + l31][ktl * 16 + khalf * 8]);
        #pragma unroll
        for (int nt = 0; nt < 2; nt++) {
            f16x8 bf = *(const f16x8*)(&bbuf[cur][(ktl * 2 + nt) * 512 + lane * 8]);
            acc[nt] = __builtin_amdgcn_mfma_f32_32x32x16_f16(
                af, bf, acc[nt], 0, 0, 0);
        }
    }

    // C layout (32x32): col i = lane&31, row = (r&3)+8*(r>>2)+4*(lane>>5)
    #pragma unroll
    for (int nt = 0; nt < 2; nt++) {
        #pragma unroll
        for (int r = 0; r < 16; r++) {
            const int erow = w * 32 + (r & 3) + 8 * (r >> 2) + 4 * khalf;
            const int e = e0 + erow;
            if (e < NE)
                msgf[(size_t)inv_s[erow] * 64 + nt * 32 + l31] = acc[nt][r];
        }
    }
}

// GRU via MFMA, v7: latency-pipelined.
//  - segment-sum: float4-vectorized (wave covers 4 rows/iter), tgt chunk staged
//    in LDS, explicit 2-deep load pipeline (next load issues before current
//    row's LDS atomics).
//  - MFMA phase: all 12 B-frags + 4 xold of each t hoisted to register arrays
//    before the MFMA chain (12-wide load ILP instead of load->MFMA lockstep).
// LDS 19.4KB -> 4 blocks/CU, grid 782 single-round. Fused pool on last step.
__global__ __launch_bounds__(256, 4) void gru_kernel(
    const float* __restrict__ msgf, const int* __restrict__ off,
    const int* __restrict__ tgt_sorted,
    float* __restrict__ x, __half* __restrict__ xh,
    const __half* __restrict__ WG,
    const float* __restrict__ bih, const float* __restrict__ bhh,
    const float* __restrict__ Wout, const float* __restrict__ bout,
    const int* __restrict__ batch, float* __restrict__ out, int dopool)
{
    __shared__ float aggs[64][68];   // 17.4 KB
    __shared__ int tgt_s[512];       // 2 KB staged targets (global fallback past 512)
    const int tid = threadIdx.x;
    const int w = tid >> 6, lane = tid & 63, m = lane & 15, quad = lane >> 4;
    const int nb0 = blockIdx.x * 64;
    const int hi = (nb0 + 64 < NN) ? nb0 + 64 : NN;
    const int r0 = off[nb0], r1 = off[hi];
    const int nrows = r1 - r0;

    // stage tgt chunk (coalesced) + zero aggs
    for (int i = tid; i < nrows && i < 512; i += 256)
        tgt_s[i] = tgt_sorted[r0 + i] - nb0;
    {
        float* a = &aggs[0][0];
        #pragma unroll
        for (int i = 0; i < 17; i++) a[i * 256 + tid] = 0.f;
    }
    __syncthreads();

    // segment-sum: lane covers 16B (float4) of row p; wave w owns rows
    // {w*4 + rsub + 16*i}; 2-deep pipeline: load(p+16) issues before atomics(p).
    {
        const int rsub = lane >> 4;
        const int c4 = (lane & 15) * 4;
        int p = w * 4 + rsub;
        bool okc = (p < nrows);
        float4 vc = make_float4(0.f, 0.f, 0.f, 0.f);
        int tc = 0;
        if (okc) {
            vc = *(const float4*)(msgf + (size_t)(r0 + p) * 64 + c4);
            tc = (p < 512) ? tgt_s[p] : (tgt_sorted[r0 + p] - nb0);
        }
        while (okc) {
            const int pn = p + 16;
            const bool okn = (pn < nrows);
            float4 vn = make_float4(0.f, 0.f, 0.f, 0.f);
            int tn = 0;
            if (okn) {
                vn = *(const float4*)(msgf + (size_t)(r0 + pn) * 64 + c4);
                tn = (pn < 512) ? tgt_s[pn] : (tgt_sorted[r0 + pn] - nb0);
            }
            atomicAdd(&aggs[tc][c4 + 0], vc.x);
            atomicAdd(&aggs[tc][c4 + 1], vc.y);
            atomicAdd(&aggs[tc][c4 + 2], vc.z);
            atomicAdd(&aggs[tc][c4 + 3], vc.w);
            p = pn; okc = okn; vc = vn; tc = tn;
        }
    }
    __syncthreads();

    const int nbase = nb0 + w * 16;
    const int anode = nbase + m;
    const bool aok = (anode < NN);

    f16x8 a_agg[2], a_x[2];
    #pragma unroll
    for (int kt = 0; kt < 2; kt++) {
        const int koff = kt * 32 + quad * 8;
        {
            const float* ap = &aggs[w * 16 + m][koff];
            float4 f0 = *(const float4*)ap;
            float4 f1 = *(const float4*)(ap + 4);
            union { __half2 h[4]; f16x8 v; } u;
            u.h[0] = __floats2half2_rn(f0.x, f0.y);
            u.h[1] = __floats2half2_rn(f0.z, f0.w);
            u.h[2] = __floats2half2_rn(f1.x, f1.y);
            u.h[3] = __floats2half2_rn(f1.z, f1.w);
            a_agg[kt] = u.v;
        }
        if (aok) {
            a_x[kt] = *(const f16x8*)(xh + (size_t)anode * 64 + koff);
        } else {
            f16x8 z;
            #pragma unroll
            for (int i = 0; i < 8; i++) z[i] = (_Float16)0;
            a_x[kt] = z;
        }
    }

    float pdr0 = 0.f, pdr1 = 0.f, pdr2 = 0.f, pdr3 = 0.f;

    #pragma unroll
    for (int t = 0; t < 4; t++) {
        const int h = t * 16 + m;

        // hoist: 12 B-fragments + 4 xold loads -> parallel issue
        f16x8 bfr[12];
        #pragma unroll
        for (int g = 0; g < 6; g++)
            #pragma unroll
            for (int kt = 0; kt < 2; kt++)
                bfr[g * 2 + kt] = *(const f16x8*)(
                    WG + (size_t)(kt * 24 + g * 4 + t) * 512 + m * 32 + quad * 8);
        float xold[4];
        #pragma unroll
        for (int r = 0; r < 4; r++) {
            const int nd = nbase + quad * 4 + r;
            xold[r] = (nd < NN) ? x[(size_t)nd * 64 + h] : 0.f;
        }

        f32x4 accg[6];
        #pragma unroll
        for (int g = 0; g < 6; g++)
            #pragma unroll
            for (int q = 0; q < 4; q++) accg[g][q] = 0.f;

        #pragma unroll
        for (int g = 0; g < 6; g++)
            #pragma unroll
            for (int kt = 0; kt < 2; kt++)
                accg[g] = __builtin_amdgcn_mfma_f32_16x16x32_f16(
                    (g < 3) ? a_agg[kt] : a_x[kt], bfr[g * 2 + kt], accg[g], 0, 0, 0);

        const float bir = bih[h], biz = bih[64 + h], bin = bih[128 + h];
        const float bhr = bhh[h], bhz = bhh[64 + h], bhn = bhh[128 + h];
        const float wo = dopool ? Wout[h] : 0.f;
        #pragma unroll
        for (int r = 0; r < 4; r++) {
            const int nd = nbase + quad * 4 + r;
            if (nd >= NN) continue;
            float ir  = accg[0][r] + bir;
            float iz  = accg[1][r] + biz;
            float in_ = accg[2][r] + bin;
            float hr  = accg[3][r] + bhr;
            float hz  = accg[4][r] + bhz;
            float hn  = accg[5][r] + bhn;
            float rg = sigm(ir + hr);
            float z  = sigm(iz + hz);
            float n  = tanh_fast(in_ + rg * hn);
            float xn = (1.0f - z) * n + z * xold[r];
            x[(size_t)nd * 64 + h] = xn;
            xh[(size_t)nd * 64 + h] = __float2half(xn);
            float c = xn * wo;
            if (r == 0) pdr0 += c; else if (r == 1) pdr1 += c;
            else if (r == 2) pdr2 += c; else pdr3 += c;
        }
    }

    if (dopool) {
        float pdr[4] = {pdr0, pdr1, pdr2, pdr3};
        #pragma unroll
        for (int r = 0; r < 4; r++) {
            float v = pdr[r];
            v += __shfl_xor(v, 1, 16);
            v += __shfl_xor(v, 2, 16);
            v += __shfl_xor(v, 4, 16);
            v += __shfl_xor(v, 8, 16);
            if (m == 0) {
                const int nd = nbase + quad * 4 + r;
                if (nd < NN) atomicAdd(out + batch[nd], v + bout[0]);
            }
        }
    }
}

extern "C" void kernel_launch(void* const* d_in, const int* in_sizes, int n_in,
                              void* d_out, int out_size, void* d_ws, size_t ws_size,
                              hipStream_t stream)
{
    const float* nf   = (const float*)d_in[0];
    const float* ef   = (const float*)d_in[1];
    const int*   Esrc = (const int*)  d_in[2];
    const int*   Etgt = (const int*)  d_in[3];
    const int*   bat  = (const int*)  d_in[4];
    const float* Win  = (const float*)d_in[5];
    const float* bin_ = (const float*)d_in[6];
    const float* We1  = (const float*)d_in[7];
    const float* be1  = (const float*)d_in[8];
    const float* We2  = (const float*)d_in[9];
    const float* be2  = (const float*)d_in[10];
    const float* Wih  = (const float*)d_in[11];
    const float* bih  = (const float*)d_in[12];
    const float* Whh  = (const float*)d_in[13];
    const float* bhh  = (const float*)d_in[14];
    const float* Wout = (const float*)d_in[15];
    const float* bout = (const float*)d_in[16];

    char* ws = (char*)d_ws;
    float*  x          = (float*)(ws);                // 12,800,000 B
    float*  msgf       = (float*)(ws + 12800000);     // 25,600,000 B
    __half* xh         = (__half*)(ws + 38400000);    //  6,400,000 B
    __half* ehh        = (__half*)(ws + 44800000);    // 12,800,000 B
    __half* Bp         = (__half*)(ws + 57600000);    //    532,480 B
    __half* WG         = (__half*)(ws + 58132480);    //     49,152 B
    int*    cnt        = (int*)   (ws + 58181632);    //    200,016 B
    int*    off        = (int*)   (ws + 58381648);    //    200,016 B
    int*    wpos       = (int*)   (ws + 58581664);    //    200,016 B
    int*    inv        = (int*)   (ws + 58781680);    //    400,000 B
    int*    tgt_sorted = (int*)   (ws + 59181680);    //    400,000 B
    int*    bsum       = (int*)   (ws + 59581680);    //      1,024 B
    int*    bscan      = (int*)   (ws + 59582704);    //      1,024 B

    hipMemsetAsync(d_out, 0, NB * sizeof(float), stream);
    hipMemsetAsync(cnt, 0, (NN + 1) * sizeof(int), stream);

    prep_kernel<<<PREP_GRID, 256, 0, stream>>>(
        nf, Win, bin_, x, xh, ef, We1, be1, ehh, We2, be2, Bp, Wih, Whh, WG);

    hist_kernel<<<(NE + 255) / 256, 256, 0, stream>>>(Etgt, cnt);
    scanA_kernel<<<NBLK_SCAN, 256, 0, stream>>>(cnt, bsum);
    scanB_kernel<<<1, 256, 0, stream>>>(bsum, bscan, off);
    scanC_kernel<<<NBLK_SCAN, 256, 0, stream>>>(cnt, bscan, off, wpos);
    scatter_kernel<<<(NE + 255) / 256, 256, 0, stream>>>(Etgt, wpos, inv, tgt_sorted);

    for (int t = 0; t < 3; t++) {
        msg_kernel<<<(NE + 127) / 128, 256, 0, stream>>>(xh, ehh, Bp, Esrc, inv, msgf);
        gru_kernel<<<(NN + 63) / 64, 256, 0, stream>>>(
            msgf, off, tgt_sorted, x, xh, WG, bih, bhh,
            Wout, bout, bat, (float*)d_out, (t == 2) ? 1 : 0);
    }
}

// Round 8
// 518.127 us; speedup vs baseline: 1.2165x; 1.0425x over previous
//
#include <hip/hip_runtime.h>
#include <hip/hip_fp16.h>

#define NN 50000   // nodes
#define NE 100000  // edges
#define NB 512     // graphs
#define NBLK_SCAN 196   // ceil(NN/256)
// H = 64, F_NODE = 16, F_EDGE = 8, T = 3

typedef _Float16 f16x8 __attribute__((ext_vector_type(8)));
typedef float f32x4   __attribute__((ext_vector_type(4)));
typedef float f32x16  __attribute__((ext_vector_type(16)));

__device__ __forceinline__ float sigm(float v) { return 1.0f / (1.0f + __expf(-v)); }
__device__ __forceinline__ float tanh_fast(float v) {
    float e = __expf(-2.0f * fabsf(v));
    float t = (1.0f - e) / (1.0f + e);
    return v < 0.f ? -t : t;
}

// ---- fused prep kernel: node_in ++ edge_l1 ++ pack_b(32x32) ++ pack_gru ----
#define PREP_GRID 38636

__global__ __launch_bounds__(256) void prep_kernel(
    const float* __restrict__ nf, const float* __restrict__ Win,
    const float* __restrict__ bin_, float* __restrict__ x, __half* __restrict__ xh,
    const float* __restrict__ ef, const float* __restrict__ We1,
    const float* __restrict__ be1, __half* __restrict__ ehh,
    const float* __restrict__ We2, const float* __restrict__ be2,
    __half* __restrict__ Bp,
    const float* __restrict__ Wih, const float* __restrict__ Whh,
    __half* __restrict__ WG)
{
    const int b = blockIdx.x;
    const int tid = threadIdx.x;
    if (b < 12500) {
        int idx = b * 256 + tid;
        int n = idx >> 6, h = idx & 63;
        float acc = bin_[h];
        #pragma unroll
        for (int f = 0; f < 16; f++) acc += nf[n * 16 + f] * Win[h * 16 + f];
        x[idx] = acc;
        xh[idx] = __float2half(acc);
    } else if (b < 37500) {
        int idx = (b - 12500) * 256 + tid;
        int e = idx >> 6, k = idx & 63;
        float acc = be1[k];
        #pragma unroll
        for (int f = 0; f < 8; f++) acc += ef[e * 8 + f] * We1[k * 8 + f];
        ehh[idx] = __float2half(fmaxf(acc, 0.0f));
    } else if (b < 38540) {
        // Pack We2 (+be2 K-ext) into 32x32x16 lane-linear B-frag order
        int idx = (b - 37500) * 256 + tid;    // 0 .. 266239 (260 kt x 1024)
        int ii = idx & 7;
        int l  = (idx >> 3) & 63;
        int nt = (idx >> 9) & 1;
        int kt = idx >> 10;
        int n  = nt * 32 + (l & 31);
        int p  = kt * 16 + ((l >> 5) << 3) + ii;
        float v;
        if (p < 4096) {
            v = We2[((size_t)(n * 64 + (p >> 6))) * 64 + (p & 63)];
        } else {
            v = be2[n * 64 + (p - 4096)];
        }
        Bp[idx] = __float2half(v);
    } else {
        // Pack GRU weights, 16x16x32 B-frag layout WG[kt][nt][n][kk]
        int idx = (b - 38540) * 256 + tid;    // 0 .. 24575
        int kk = idx & 31;
        int n  = (idx >> 5) & 15;
        int nt = (idx >> 9) % 24;
        int kt = (idx >> 9) / 24;
        int k = kt * 32 + kk;
        int col192 = (nt % 12) * 16 + n;
        int gate = col192 >> 6, h = col192 & 63;
        const float* src = (nt < 12) ? Wih : Whh;
        WG[idx] = __float2half(src[((size_t)(gate * 64 + h)) * 64 + k]);
    }
}

// ---- counting sort of edges by target ----

__global__ __launch_bounds__(256) void hist_kernel(
    const int* __restrict__ Etgt, int* __restrict__ cnt)
{
    int e = blockIdx.x * 256 + threadIdx.x;
    if (e < NE) atomicAdd(&cnt[Etgt[e]], 1);
}

__device__ __forceinline__ int block_excl_scan(int v, int tid, int* lds)
{
    int lane = tid & 63, w = tid >> 6;
    int incl = v;
    #pragma unroll
    for (int d = 1; d < 64; d <<= 1) {
        int u = __shfl_up(incl, d, 64);
        if (lane >= d) incl += u;
    }
    if (lane == 63) lds[w] = incl;
    __syncthreads();
    if (tid == 0) {
        int a = lds[0], b = lds[1], c = lds[2];
        lds[4] = 0; lds[5] = a; lds[6] = a + b; lds[7] = a + b + c;
    }
    __syncthreads();
    return incl - v + lds[4 + w];
}

__global__ __launch_bounds__(256) void scanA_kernel(
    const int* __restrict__ cnt, int* __restrict__ bsum)
{
    __shared__ int s4[4];
    int tid = threadIdx.x;
    int idx = blockIdx.x * 256 + tid;
    int v = (idx < NN) ? cnt[idx] : 0;
    #pragma unroll
    for (int d = 1; d < 64; d <<= 1) v += __shfl_xor(v, d, 64);
    if ((tid & 63) == 0) s4[tid >> 6] = v;
    __syncthreads();
    if (tid == 0) bsum[blockIdx.x] = s4[0] + s4[1] + s4[2] + s4[3];
}

__global__ __launch_bounds__(256) void scanB_kernel(
    const int* __restrict__ bsum, int* __restrict__ bscan, int* __restrict__ off)
{
    __shared__ int lds[8];
    int tid = threadIdx.x;
    int v = (tid < NBLK_SCAN) ? bsum[tid] : 0;
    int ex = block_excl_scan(v, tid, lds);
    if (tid < NBLK_SCAN) bscan[tid] = ex;
    if (tid == NBLK_SCAN) off[NN] = ex;   // total
}

__global__ __launch_bounds__(256) void scanC_kernel(
    const int* __restrict__ cnt, const int* __restrict__ bscan,
    int* __restrict__ off, int* __restrict__ wpos)
{
    __shared__ int lds[8];
    int tid = threadIdx.x;
    int idx = blockIdx.x * 256 + tid;
    int v = (idx < NN) ? cnt[idx] : 0;
    int ex = block_excl_scan(v, tid, lds) + bscan[blockIdx.x];
    if (idx < NN) { off[idx] = ex; wpos[idx] = ex; }
}

__global__ __launch_bounds__(256) void scatter_kernel(
    const int* __restrict__ Etgt, int* __restrict__ wpos, int* __restrict__ inv)
{
    int e = blockIdx.x * 256 + threadIdx.x;
    if (e < NE) {
        int p = atomicAdd(&wpos[Etgt[e]], 1);
        inv[e] = p;
    }
}

// Fused message GEMM (unchanged): 32x32x16 MFMA, 128 edges/block,
// 35.3KB LDS -> 4 blocks/CU, grid 782 single-round. No atomics.
__global__ __launch_bounds__(256, 4) void msg_kernel(
    const __half* __restrict__ xh, const __half* __restrict__ ehh,
    const __half* __restrict__ Bp,
    const int* __restrict__ Esrc, const int* __restrict__ inv,
    float* __restrict__ msgf)
{
    __shared__ __align__(16) __half xs[128][72];     // 18432 B
    __shared__ __align__(16) __half bbuf[2][4096];   // 16384 B
    __shared__ int inv_s[128];
    const int tid = threadIdx.x;
    const int e0 = blockIdx.x * 128;
    const int w = tid >> 6, lane = tid & 63;
    const int l31 = lane & 31, khalf = lane >> 5;

    {   // stage gathered f16 source rows: 128 rows, 2 threads per row (64B each)
        const int r = tid >> 1, part = tid & 1;
        const int e = e0 + r;
        const bool ok = (e < NE);
        const int src = ok ? Esrc[e] : 0;
        if (part == 0) inv_s[r] = ok ? inv[e] : 0;
        const uint4* xsrc = (const uint4*)(xh + (size_t)src * 64 + part * 32);
        __half* dst = &xs[r][part * 32];
        #pragma unroll
        for (int i = 0; i < 4; i++) {
            uint4 v = ok ? xsrc[i] : make_uint4(0, 0, 0, 0);
            *(uint4*)(dst + i * 8) = v;
        }
    }

    {   // prologue: B tile j=0 -> bbuf[0]
        const uint4* s = (const uint4*)Bp;
        uint4 v0 = s[tid], v1 = s[256 + tid];
        ((uint4*)bbuf[0])[tid] = v0;
        ((uint4*)bbuf[0])[256 + tid] = v1;
    }

    const int eMine = e0 + w * 32 + l31;
    __half2 ehc2[4][4];
    if (eMine < NE) {
        #pragma unroll
        for (int kt = 0; kt < 4; kt++) {
            union { uint4 u; __half2 h[4]; } u0;
            u0.u = *(const uint4*)(ehh + (size_t)eMine * 64 + kt * 16 + khalf * 8);
            #pragma unroll
            for (int q = 0; q < 4; q++) ehc2[kt][q] = u0.h[q];
        }
    } else {
        __half2 z = __halves2half2(__float2half(0.f), __float2half(0.f));
        #pragma unroll
        for (int kt = 0; kt < 4; kt++)
            #pragma unroll
            for (int q = 0; q < 4; q++) ehc2[kt][q] = z;
    }

    f32x16 acc[2];
    #pragma unroll
    for (int nt = 0; nt < 2; nt++)
        #pragma unroll
        for (int q = 0; q < 16; q++) acc[nt][q] = 0.f;

    __syncthreads();

    int cur = 0;
    #pragma unroll 1
    for (int j = 0; j < 64; j++) {
        const uint4* s = (const uint4*)(Bp + (size_t)(j + 1) * 4096);
        uint4 p0 = s[tid];
        uint4 p1 = s[256 + tid];

        const __half xv = xs[w * 32 + l31][j];
        const __half2 xb = __half2half2(xv);

        #pragma unroll
        for (int kt = 0; kt < 4; kt++) {
            union { __half2 h[4]; f16x8 v; } u;
            #pragma unroll
            for (int q = 0; q < 4; q++) u.h[q] = __hmul2(xb, ehc2[kt][q]);
            #pragma unroll
            for (int nt = 0; nt < 2; nt++) {
                f16x8 bf = *(const f16x8*)(&bbuf[cur][(kt * 2 + nt) * 512 + lane * 8]);
                acc[nt] = __builtin_amdgcn_mfma_f32_32x32x16_f16(
                    u.v, bf, acc[nt], 0, 0, 0);
            }
        }

        uint4* d = (uint4*)bbuf[cur ^ 1];
        d[tid] = p0;
        d[256 + tid] = p1;
        __syncthreads();
        cur ^= 1;
    }

    // be2 K-extension
    #pragma unroll
    for (int ktl = 0; ktl < 4; ktl++) {
        f16x8 af = *(const f16x8*)(&xs[w * 32 + l31][ktl * 16 + khalf * 8]);
        #pragma unroll
        for (int nt = 0; nt < 2; nt++) {
            f16x8 bf = *(const f16x8*)(&bbuf[cur][(ktl * 2 + nt) * 512 + lane * 8]);
            acc[nt] = __builtin_amdgcn_mfma_f32_32x32x16_f16(
                af, bf, acc[nt], 0, 0, 0);
        }
    }

    // C layout (32x32): col i = lane&31, row = (r&3)+8*(r>>2)+4*(lane>>5)
    #pragma unroll
    for (int nt = 0; nt < 2; nt++) {
        #pragma unroll
        for (int r = 0; r < 16; r++) {
            const int erow = w * 32 + (r & 3) + 8 * (r >> 2) + 4 * khalf;
            const int e = e0 + erow;
            if (e < NE)
                msgf[(size_t)inv_s[erow] * 64 + nt * 32 + l31] = acc[nt][r];
        }
    }
}

// Segment-sum, v8: one 16-lane group per NODE. Group reads its node's
// contiguous sorted msgf rows (avg 2), sums in registers, stores the 64-wide
// row as f16. No LDS, no atomics, no barriers. Grid 3125 -> 12.5K waves.
__global__ __launch_bounds__(256) void segsum_kernel(
    const float* __restrict__ msgf, const int* __restrict__ off,
    __half* __restrict__ aggh)
{
    const int tid = threadIdx.x;
    const int n = blockIdx.x * 16 + (tid >> 4);
    const int c4 = (tid & 15) * 4;
    if (n >= NN) return;
    const int r0 = off[n], r1 = off[n + 1];
    float4 acc = make_float4(0.f, 0.f, 0.f, 0.f);
    for (int p = r0; p < r1; ++p) {
        float4 v = *(const float4*)(msgf + (size_t)p * 64 + c4);
        acc.x += v.x; acc.y += v.y; acc.z += v.z; acc.w += v.w;
    }
    union { __half2 h[2]; unsigned long long u; } pk;
    pk.h[0] = __floats2half2_rn(acc.x, acc.y);
    pk.h[1] = __floats2half2_rn(acc.z, acc.w);
    *(unsigned long long*)(aggh + (size_t)n * 64 + c4) = pk.u;
}

// GRU via MFMA, v8: no LDS, no barriers. A-frags straight from aggh (f16) and
// xh; B-frags from L2-hot WG. 6 blocks/CU co-resident. Fused pool on last step.
__global__ __launch_bounds__(256, 6) void gru_kernel(
    const __half* __restrict__ aggh,
    float* __restrict__ x, __half* __restrict__ xh,
    const __half* __restrict__ WG,
    const float* __restrict__ bih, const float* __restrict__ bhh,
    const float* __restrict__ Wout, const float* __restrict__ bout,
    const int* __restrict__ batch, float* __restrict__ out, int dopool)
{
    const int tid = threadIdx.x;
    const int w = tid >> 6, lane = tid & 63, m = lane & 15, quad = lane >> 4;
    const int nbase = blockIdx.x * 64 + w * 16;
    const int anode = nbase + m;
    const bool aok = (anode < NN);

    f16x8 a_agg[2], a_x[2];
    #pragma unroll
    for (int kt = 0; kt < 2; kt++) {
        const int koff = kt * 32 + quad * 8;
        if (aok) {
            a_agg[kt] = *(const f16x8*)(aggh + (size_t)anode * 64 + koff);
            a_x[kt]   = *(const f16x8*)(xh   + (size_t)anode * 64 + koff);
        } else {
            f16x8 z;
            #pragma unroll
            for (int i = 0; i < 8; i++) z[i] = (_Float16)0;
            a_agg[kt] = z; a_x[kt] = z;
        }
    }

    float pdr0 = 0.f, pdr1 = 0.f, pdr2 = 0.f, pdr3 = 0.f;

    #pragma unroll
    for (int t = 0; t < 4; t++) {
        const int h = t * 16 + m;

        f16x8 bfr[12];
        #pragma unroll
        for (int g = 0; g < 6; g++)
            #pragma unroll
            for (int kt = 0; kt < 2; kt++)
                bfr[g * 2 + kt] = *(const f16x8*)(
                    WG + (size_t)(kt * 24 + g * 4 + t) * 512 + m * 32 + quad * 8);
        float xold[4];
        #pragma unroll
        for (int r = 0; r < 4; r++) {
            const int nd = nbase + quad * 4 + r;
            xold[r] = (nd < NN) ? x[(size_t)nd * 64 + h] : 0.f;
        }

        f32x4 accg[6];
        #pragma unroll
        for (int g = 0; g < 6; g++)
            #pragma unroll
            for (int q = 0; q < 4; q++) accg[g][q] = 0.f;

        #pragma unroll
        for (int g = 0; g < 6; g++)
            #pragma unroll
            for (int kt = 0; kt < 2; kt++)
                accg[g] = __builtin_amdgcn_mfma_f32_16x16x32_f16(
                    (g < 3) ? a_agg[kt] : a_x[kt], bfr[g * 2 + kt], accg[g], 0, 0, 0);

        const float bir = bih[h], biz = bih[64 + h], bin = bih[128 + h];
        const float bhr = bhh[h], bhz = bhh[64 + h], bhn = bhh[128 + h];
        const float wo = dopool ? Wout[h] : 0.f;
        #pragma unroll
        for (int r = 0; r < 4; r++) {
            const int nd = nbase + quad * 4 + r;
            if (nd >= NN) continue;
            float ir  = accg[0][r] + bir;
            float iz  = accg[1][r] + biz;
            float in_ = accg[2][r] + bin;
            float hr  = accg[3][r] + bhr;
            float hz  = accg[4][r] + bhz;
            float hn  = accg[5][r] + bhn;
            float rg = sigm(ir + hr);
            float z  = sigm(iz + hz);
            float n  = tanh_fast(in_ + rg * hn);
            float xn = (1.0f - z) * n + z * xold[r];
            x[(size_t)nd * 64 + h] = xn;
            xh[(size_t)nd * 64 + h] = __float2half(xn);
            float c = xn * wo;
            if (r == 0) pdr0 += c; else if (r == 1) pdr1 += c;
            else if (r == 2) pdr2 += c; else pdr3 += c;
        }
    }

    if (dopool) {
        float pdr[4] = {pdr0, pdr1, pdr2, pdr3};
        #pragma unroll
        for (int r = 0; r < 4; r++) {
            float v = pdr[r];
            v += __shfl_xor(v, 1, 16);
            v += __shfl_xor(v, 2, 16);
            v += __shfl_xor(v, 4, 16);
            v += __shfl_xor(v, 8, 16);
            if (m == 0) {
                const int nd = nbase + quad * 4 + r;
                if (nd < NN) atomicAdd(out + batch[nd], v + bout[0]);
            }
        }
    }
}

extern "C" void kernel_launch(void* const* d_in, const int* in_sizes, int n_in,
                              void* d_out, int out_size, void* d_ws, size_t ws_size,
                              hipStream_t stream)
{
    const float* nf   = (const float*)d_in[0];
    const float* ef   = (const float*)d_in[1];
    const int*   Esrc = (const int*)  d_in[2];
    const int*   Etgt = (const int*)  d_in[3];
    const int*   bat  = (const int*)  d_in[4];
    const float* Win  = (const float*)d_in[5];
    const float* bin_ = (const float*)d_in[6];
    const float* We1  = (const float*)d_in[7];
    const float* be1  = (const float*)d_in[8];
    const float* We2  = (const float*)d_in[9];
    const float* be2  = (const float*)d_in[10];
    const float* Wih  = (const float*)d_in[11];
    const float* bih  = (const float*)d_in[12];
    const float* Whh  = (const float*)d_in[13];
    const float* bhh  = (const float*)d_in[14];
    const float* Wout = (const float*)d_in[15];
    const float* bout = (const float*)d_in[16];

    char* ws = (char*)d_ws;
    float*  x     = (float*)(ws);                // 12,800,000 B
    float*  msgf  = (float*)(ws + 12800000);     // 25,600,000 B
    __half* xh    = (__half*)(ws + 38400000);    //  6,400,000 B
    __half* ehh   = (__half*)(ws + 44800000);    // 12,800,000 B
    __half* Bp    = (__half*)(ws + 57600000);    //    532,480 B
    __half* WG    = (__half*)(ws + 58132480);    //     49,152 B
    int*    cnt   = (int*)   (ws + 58181632);    //    200,016 B
    int*    off   = (int*)   (ws + 58381648);    //    200,016 B
    int*    wpos  = (int*)   (ws + 58581664);    //    200,016 B
    int*    inv   = (int*)   (ws + 58781680);    //    400,000 B
    __half* aggh  = (__half*)(ws + 59181680);    //  6,400,000 B
    int*    bsum  = (int*)   (ws + 65581680);    //      1,024 B
    int*    bscan = (int*)   (ws + 65582704);    //      1,024 B

    hipMemsetAsync(d_out, 0, NB * sizeof(float), stream);
    hipMemsetAsync(cnt, 0, (NN + 1) * sizeof(int), stream);

    prep_kernel<<<PREP_GRID, 256, 0, stream>>>(
        nf, Win, bin_, x, xh, ef, We1, be1, ehh, We2, be2, Bp, Wih, Whh, WG);

    hist_kernel<<<(NE + 255) / 256, 256, 0, stream>>>(Etgt, cnt);
    scanA_kernel<<<NBLK_SCAN, 256, 0, stream>>>(cnt, bsum);
    scanB_kernel<<<1, 256, 0, stream>>>(bsum, bscan, off);
    scanC_kernel<<<NBLK_SCAN, 256, 0, stream>>>(cnt, bscan, off, wpos);
    scatter_kernel<<<(NE + 255) / 256, 256, 0, stream>>>(Etgt, wpos, inv);

    for (int t = 0; t < 3; t++) {
        msg_kernel<<<(NE + 127) / 128, 256, 0, stream>>>(xh, ehh, Bp, Esrc, inv, msgf);
        segsum_kernel<<<(NN + 15) / 16, 256, 0, stream>>>(msgf, off, aggh);
        gru_kernel<<<(NN + 63) / 64, 256, 0, stream>>>(
            aggh, x, xh, WG, bih, bhh,
            Wout, bout, bat, (float*)d_out, (t == 2) ? 1 : 0);
    }
}

// Round 9
// 473.529 us; speedup vs baseline: 1.3310x; 1.0942x over previous
//
#include <hip/hip_runtime.h>
#include <hip/hip_fp16.h>

#define NN 50000   // nodes
#define NE 100000  // edges
#define NB 512     // graphs
#define NBLK_SCAN 196   // ceil(NN/256)
// H = 64, F_NODE = 16, F_EDGE = 8, T = 3

typedef _Float16 f16x8 __attribute__((ext_vector_type(8)));
typedef float f32x4   __attribute__((ext_vector_type(4)));
typedef float f32x16  __attribute__((ext_vector_type(16)));

__device__ __forceinline__ float sigm(float v) { return 1.0f / (1.0f + __expf(-v)); }
__device__ __forceinline__ float tanh_fast(float v) {
    float e = __expf(-2.0f * fabsf(v));
    float t = (1.0f - e) / (1.0f + e);
    return v < 0.f ? -t : t;
}

// ---- fused prep kernel: node_in ++ edge_l1 ++ pack_b(32x32) ++ pack_gru ----
#define PREP_GRID 38636

__global__ __launch_bounds__(256) void prep_kernel(
    const float* __restrict__ nf, const float* __restrict__ Win,
    const float* __restrict__ bin_, float* __restrict__ x, __half* __restrict__ xh,
    const float* __restrict__ ef, const float* __restrict__ We1,
    const float* __restrict__ be1, __half* __restrict__ ehh,
    const float* __restrict__ We2, const float* __restrict__ be2,
    __half* __restrict__ Bp,
    const float* __restrict__ Wih, const float* __restrict__ Whh,
    __half* __restrict__ WG)
{
    const int b = blockIdx.x;
    const int tid = threadIdx.x;
    if (b < 12500) {
        int idx = b * 256 + tid;
        int n = idx >> 6, h = idx & 63;
        float acc = bin_[h];
        #pragma unroll
        for (int f = 0; f < 16; f++) acc += nf[n * 16 + f] * Win[h * 16 + f];
        x[idx] = acc;
        xh[idx] = __float2half(acc);
    } else if (b < 37500) {
        int idx = (b - 12500) * 256 + tid;
        int e = idx >> 6, k = idx & 63;
        float acc = be1[k];
        #pragma unroll
        for (int f = 0; f < 8; f++) acc += ef[e * 8 + f] * We1[k * 8 + f];
        ehh[idx] = __float2half(fmaxf(acc, 0.0f));
    } else if (b < 38540) {
        // Pack We2 (+be2 K-ext) into 32x32x16 lane-linear B-frag order
        int idx = (b - 37500) * 256 + tid;    // 0 .. 266239 (260 kt x 1024)
        int ii = idx & 7;
        int l  = (idx >> 3) & 63;
        int nt = (idx >> 9) & 1;
        int kt = idx >> 10;
        int n  = nt * 32 + (l & 31);
        int p  = kt * 16 + ((l >> 5) << 3) + ii;
        float v;
        if (p < 4096) {
            v = We2[((size_t)(n * 64 + (p >> 6))) * 64 + (p & 63)];
        } else {
            v = be2[n * 64 + (p - 4096)];
        }
        Bp[idx] = __float2half(v);
    } else {
        // Pack GRU weights, 16x16x32 B-frag layout WG[kt][nt][n][kk]
        int idx = (b - 38540) * 256 + tid;    // 0 .. 24575
        int kk = idx & 31;
        int n  = (idx >> 5) & 15;
        int nt = (idx >> 9) % 24;
        int kt = (idx >> 9) / 24;
        int k = kt * 32 + kk;
        int col192 = (nt % 12) * 16 + n;
        int gate = col192 >> 6, h = col192 & 63;
        const float* src = (nt < 12) ? Wih : Whh;
        WG[idx] = __float2half(src[((size_t)(gate * 64 + h)) * 64 + k]);
    }
}

// ---- counting sort of edges by target ----

__global__ __launch_bounds__(256) void hist_kernel(
    const int* __restrict__ Etgt, int* __restrict__ cnt)
{
    int e = blockIdx.x * 256 + threadIdx.x;
    if (e < NE) atomicAdd(&cnt[Etgt[e]], 1);
}

__device__ __forceinline__ int block_excl_scan(int v, int tid, int* lds)
{
    int lane = tid & 63, w = tid >> 6;
    int incl = v;
    #pragma unroll
    for (int d = 1; d < 64; d <<= 1) {
        int u = __shfl_up(incl, d, 64);
        if (lane >= d) incl += u;
    }
    if (lane == 63) lds[w] = incl;
    __syncthreads();
    if (tid == 0) {
        int a = lds[0], b = lds[1], c = lds[2];
        lds[4] = 0; lds[5] = a; lds[6] = a + b; lds[7] = a + b + c;
    }
    __syncthreads();
    return incl - v + lds[4 + w];
}

__global__ __launch_bounds__(256) void scanA_kernel(
    const int* __restrict__ cnt, int* __restrict__ bsum)
{
    __shared__ int s4[4];
    int tid = threadIdx.x;
    int idx = blockIdx.x * 256 + tid;
    int v = (idx < NN) ? cnt[idx] : 0;
    #pragma unroll
    for (int d = 1; d < 64; d <<= 1) v += __shfl_xor(v, d, 64);
    if ((tid & 63) == 0) s4[tid >> 6] = v;
    __syncthreads();
    if (tid == 0) bsum[blockIdx.x] = s4[0] + s4[1] + s4[2] + s4[3];
}

__global__ __launch_bounds__(256) void scanB_kernel(
    const int* __restrict__ bsum, int* __restrict__ bscan, int* __restrict__ off)
{
    __shared__ int lds[8];
    int tid = threadIdx.x;
    int v = (tid < NBLK_SCAN) ? bsum[tid] : 0;
    int ex = block_excl_scan(v, tid, lds);
    if (tid < NBLK_SCAN) bscan[tid] = ex;
    if (tid == NBLK_SCAN) off[NN] = ex;   // total
}

__global__ __launch_bounds__(256) void scanC_kernel(
    const int* __restrict__ cnt, const int* __restrict__ bscan,
    int* __restrict__ off, int* __restrict__ wpos)
{
    __shared__ int lds[8];
    int tid = threadIdx.x;
    int idx = blockIdx.x * 256 + tid;
    int v = (idx < NN) ? cnt[idx] : 0;
    int ex = block_excl_scan(v, tid, lds) + bscan[blockIdx.x];
    if (idx < NN) { off[idx] = ex; wpos[idx] = ex; }
}

__global__ __launch_bounds__(256) void scatter_kernel(
    const int* __restrict__ Etgt, int* __restrict__ wpos, int* __restrict__ inv)
{
    int e = blockIdx.x * 256 + threadIdx.x;
    if (e < NE) {
        int p = atomicAdd(&wpos[Etgt[e]], 1);
        inv[e] = p;
    }
}

// Fused message GEMM (unchanged): 32x32x16 MFMA, 128 edges/block,
// 35.3KB LDS -> 4 blocks/CU, grid 782 single-round. No atomics.
__global__ __launch_bounds__(256, 4) void msg_kernel(
    const __half* __restrict__ xh, const __half* __restrict__ ehh,
    const __half* __restrict__ Bp,
    const int* __restrict__ Esrc, const int* __restrict__ inv,
    float* __restrict__ msgf)
{
    __shared__ __align__(16) __half xs[128][72];     // 18432 B
    __shared__ __align__(16) __half bbuf[2][4096];   // 16384 B
    __shared__ int inv_s[128];
    const int tid = threadIdx.x;
    const int e0 = blockIdx.x * 128;
    const int w = tid >> 6, lane = tid & 63;
    const int l31 = lane & 31, khalf = lane >> 5;

    {   // stage gathered f16 source rows: 128 rows, 2 threads per row (64B each)
        const int r = tid >> 1, part = tid & 1;
        const int e = e0 + r;
        const bool ok = (e < NE);
        const int src = ok ? Esrc[e] : 0;
        if (part == 0) inv_s[r] = ok ? inv[e] : 0;
        const uint4* xsrc = (const uint4*)(xh + (size_t)src * 64 + part * 32);
        __half* dst = &xs[r][part * 32];
        #pragma unroll
        for (int i = 0; i < 4; i++) {
            uint4 v = ok ? xsrc[i] : make_uint4(0, 0, 0, 0);
            *(uint4*)(dst + i * 8) = v;
        }
    }

    {   // prologue: B tile j=0 -> bbuf[0]
        const uint4* s = (const uint4*)Bp;
        uint4 v0 = s[tid], v1 = s[256 + tid];
        ((uint4*)bbuf[0])[tid] = v0;
        ((uint4*)bbuf[0])[256 + tid] = v1;
    }

    const int eMine = e0 + w * 32 + l31;
    __half2 ehc2[4][4];
    if (eMine < NE) {
        #pragma unroll
        for (int kt = 0; kt < 4; kt++) {
            union { uint4 u; __half2 h[4]; } u0;
            u0.u = *(const uint4*)(ehh + (size_t)eMine * 64 + kt * 16 + khalf * 8);
            #pragma unroll
            for (int q = 0; q < 4; q++) ehc2[kt][q] = u0.h[q];
        }
    } else {
        __half2 z = __halves2half2(__float2half(0.f), __float2half(0.f));
        #pragma unroll
        for (int kt = 0; kt < 4; kt++)
            #pragma unroll
            for (int q = 0; q < 4; q++) ehc2[kt][q] = z;
    }

    f32x16 acc[2];
    #pragma unroll
    for (int nt = 0; nt < 2; nt++)
        #pragma unroll
        for (int q = 0; q < 16; q++) acc[nt][q] = 0.f;

    __syncthreads();

    int cur = 0;
    #pragma unroll 1
    for (int j = 0; j < 64; j++) {
        const uint4* s = (const uint4*)(Bp + (size_t)(j + 1) * 4096);
        uint4 p0 = s[tid];
        uint4 p1 = s[256 + tid];

        const __half xv = xs[w * 32 + l31][j];
        const __half2 xb = __half2half2(xv);

        #pragma unroll
        for (int kt = 0; kt < 4; kt++) {
            union { __half2 h[4]; f16x8 v; } u;
            #pragma unroll
            for (int q = 0; q < 4; q++) u.h[q] = __hmul2(xb, ehc2[kt][q]);
            #pragma unroll
            for (int nt = 0; nt < 2; nt++) {
                f16x8 bf = *(const f16x8*)(&bbuf[cur][(kt * 2 + nt) * 512 + lane * 8]);
                acc[nt] = __builtin_amdgcn_mfma_f32_32x32x16_f16(
                    u.v, bf, acc[nt], 0, 0, 0);
            }
        }

        uint4* d = (uint4*)bbuf[cur ^ 1];
        d[tid] = p0;
        d[256 + tid] = p1;
        __syncthreads();
        cur ^= 1;
    }

    // be2 K-extension
    #pragma unroll
    for (int ktl = 0; ktl < 4; ktl++) {
        f16x8 af = *(const f16x8*)(&xs[w * 32 + l31][ktl * 16 + khalf * 8]);
        #pragma unroll
        for (int nt = 0; nt < 2; nt++) {
            f16x8 bf = *(const f16x8*)(&bbuf[cur][(ktl * 2 + nt) * 512 + lane * 8]);
            acc[nt] = __builtin_amdgcn_mfma_f32_32x32x16_f16(
                af, bf, acc[nt], 0, 0, 0);
        }
    }

    // C layout (32x32): col i = lane&31, row = (r&3)+8*(r>>2)+4*(lane>>5)
    #pragma unroll
    for (int nt = 0; nt < 2; nt++) {
        #pragma unroll
        for (int r = 0; r < 16; r++) {
            const int erow = w * 32 + (r & 3) + 8 * (r >> 2) + 4 * khalf;
            const int e = e0 + erow;
            if (e < NE)
                msgf[(size_t)inv_s[erow] * 64 + nt * 32 + l31] = acc[nt][r];
        }
    }
}

// Segment-sum (unchanged): one 16-lane group per node, full-line f16 row out.
__global__ __launch_bounds__(256) void segsum_kernel(
    const float* __restrict__ msgf, const int* __restrict__ off,
    __half* __restrict__ aggh)
{
    const int tid = threadIdx.x;
    const int n = blockIdx.x * 16 + (tid >> 4);
    const int c4 = (tid & 15) * 4;
    if (n >= NN) return;
    const int r0 = off[n], r1 = off[n + 1];
    float4 acc = make_float4(0.f, 0.f, 0.f, 0.f);
    for (int p = r0; p < r1; ++p) {
        float4 v = *(const float4*)(msgf + (size_t)p * 64 + c4);
        acc.x += v.x; acc.y += v.y; acc.z += v.z; acc.w += v.w;
    }
    union { __half2 h[2]; unsigned long long u; } pk;
    pk.h[0] = __floats2half2_rn(acc.x, acc.y);
    pk.h[1] = __floats2half2_rn(acc.z, acc.w);
    *(unsigned long long*)(aggh + (size_t)n * 64 + c4) = pk.u;
}

// GRU via MFMA, v9: ALL global traffic full-line coalesced via LDS transpose.
//  stage-in: x rows (f32, 16KB) + aggh rows (f16, 9KB) linear -> LDS
//  compute: A-frags from LDS; B-frags from L2-hot WG; MFMA; gate math;
//           xold read from LDS slot, xn written back IN PLACE (unique owner;
//           each wave touches only its own 16-row slice -> no cross-wave hazard)
//  stage-out: linear pass, 64B f32 + 32B f16 per thread, wave-contiguous.
// LDS 26.6KB -> 4 blocks/CU, grid 782 single-round. Fused pool on last step.
__global__ __launch_bounds__(256, 4) void gru_kernel(
    const __half* __restrict__ aggh,
    float* __restrict__ x, __half* __restrict__ xh,
    const __half* __restrict__ WG,
    const float* __restrict__ bih, const float* __restrict__ bhh,
    const float* __restrict__ Wout, const float* __restrict__ bout,
    const int* __restrict__ batch, float* __restrict__ out, int dopool)
{
    __shared__ __align__(16) float xs[64][68];    // 17408 B
    __shared__ __align__(16) __half as[64][72];   //  9216 B
    const int tid = threadIdx.x;
    const int w = tid >> 6, lane = tid & 63, m = lane & 15, quad = lane >> 4;
    const int nb0 = blockIdx.x * 64;

    // stage-in: x rows, coalesced float4 (1024 float4 = 16KB)
    #pragma unroll
    for (int i = 0; i < 4; i++) {
        int f4 = i * 256 + tid;
        int row = f4 >> 4, c4 = (f4 & 15) * 4;
        int n = nb0 + row;
        float4 v = (n < NN) ? *(const float4*)(x + (size_t)n * 64 + c4)
                            : make_float4(0.f, 0.f, 0.f, 0.f);
        *(float4*)(&xs[row][c4]) = v;
    }
    // stage-in: aggh rows, coalesced uint4 (512 uint4 = 8KB)
    #pragma unroll
    for (int i = 0; i < 2; i++) {
        int u4 = i * 256 + tid;
        int row = u4 >> 3, c8 = (u4 & 7) * 8;
        int n = nb0 + row;
        uint4 v = (n < NN) ? *(const uint4*)(aggh + (size_t)n * 64 + c8)
                           : make_uint4(0, 0, 0, 0);
        *(uint4*)(&as[row][c8]) = v;
    }
    __syncthreads();

    // A fragments from LDS (rows >= NN staged as zero)
    const int arow = w * 16 + m;
    f16x8 a_agg[2], a_x[2];
    #pragma unroll
    for (int kt = 0; kt < 2; kt++) {
        const int koff = kt * 32 + quad * 8;
        a_agg[kt] = *(const f16x8*)(&as[arow][koff]);
        const float* ap = &xs[arow][koff];
        float4 f0 = *(const float4*)ap;
        float4 f1 = *(const float4*)(ap + 4);
        union { __half2 h[4]; f16x8 v; } u;
        u.h[0] = __floats2half2_rn(f0.x, f0.y);
        u.h[1] = __floats2half2_rn(f0.z, f0.w);
        u.h[2] = __floats2half2_rn(f1.x, f1.y);
        u.h[3] = __floats2half2_rn(f1.z, f1.w);
        a_x[kt] = u.v;
    }

    float pdr0 = 0.f, pdr1 = 0.f, pdr2 = 0.f, pdr3 = 0.f;

    #pragma unroll
    for (int t = 0; t < 4; t++) {
        const int h = t * 16 + m;

        f16x8 bfr[12];
        #pragma unroll
        for (int g = 0; g < 6; g++)
            #pragma unroll
            for (int kt = 0; kt < 2; kt++)
                bfr[g * 2 + kt] = *(const f16x8*)(
                    WG + (size_t)(kt * 24 + g * 4 + t) * 512 + m * 32 + quad * 8);

        f32x4 accg[6];
        #pragma unroll
        for (int g = 0; g < 6; g++)
            #pragma unroll
            for (int q = 0; q < 4; q++) accg[g][q] = 0.f;

        #pragma unroll
        for (int g = 0; g < 6; g++)
            #pragma unroll
            for (int kt = 0; kt < 2; kt++)
                accg[g] = __builtin_amdgcn_mfma_f32_16x16x32_f16(
                    (g < 3) ? a_agg[kt] : a_x[kt], bfr[g * 2 + kt], accg[g], 0, 0, 0);

        const float bir = bih[h], biz = bih[64 + h], bin = bih[128 + h];
        const float bhr = bhh[h], bhz = bhh[64 + h], bhn = bhh[128 + h];
        const float wo = dopool ? Wout[h] : 0.f;
        #pragma unroll
        for (int r = 0; r < 4; r++) {
            const int lrow = w * 16 + quad * 4 + r;   // this wave's own slice
            float xold = xs[lrow][h];
            float ir  = accg[0][r] + bir;
            float iz  = accg[1][r] + biz;
            float in_ = accg[2][r] + bin;
            float hr  = accg[3][r] + bhr;
            float hz  = accg[4][r] + bhz;
            float hn  = accg[5][r] + bhn;
            float rg = sigm(ir + hr);
            float z  = sigm(iz + hz);
            float n  = tanh_fast(in_ + rg * hn);
            float xn = (1.0f - z) * n + z * xold;
            xs[lrow][h] = xn;                          // in-place, unique owner
            float c = xn * wo;
            if (r == 0) pdr0 += c; else if (r == 1) pdr1 += c;
            else if (r == 2) pdr2 += c; else pdr3 += c;
        }
    }

    __syncthreads();

    // stage-out: linear full-line writes (thread = 16 consecutive floats)
    {
        const int row = tid >> 2, c0 = (tid & 3) * 16;
        const int n = nb0 + row;
        if (n < NN) {
            float4 v0 = *(const float4*)(&xs[row][c0]);
            float4 v1 = *(const float4*)(&xs[row][c0 + 4]);
            float4 v2 = *(const float4*)(&xs[row][c0 + 8]);
            float4 v3 = *(const float4*)(&xs[row][c0 + 12]);
            float* xg = x + (size_t)n * 64 + c0;
            *(float4*)(xg)      = v0;
            *(float4*)(xg + 4)  = v1;
            *(float4*)(xg + 8)  = v2;
            *(float4*)(xg + 12) = v3;
            union { __half2 h[4]; uint4 u; } pa, pb;
            pa.h[0] = __floats2half2_rn(v0.x, v0.y);
            pa.h[1] = __floats2half2_rn(v0.z, v0.w);
            pa.h[2] = __floats2half2_rn(v1.x, v1.y);
            pa.h[3] = __floats2half2_rn(v1.z, v1.w);
            pb.h[0] = __floats2half2_rn(v2.x, v2.y);
            pb.h[1] = __floats2half2_rn(v2.z, v2.w);
            pb.h[2] = __floats2half2_rn(v3.x, v3.y);
            pb.h[3] = __floats2half2_rn(v3.z, v3.w);
            uint4* xhg = (uint4*)(xh + (size_t)n * 64 + c0);
            xhg[0] = pa.u;
            xhg[1] = pb.u;
        }
    }

    if (dopool) {
        float pdr[4] = {pdr0, pdr1, pdr2, pdr3};
        #pragma unroll
        for (int r = 0; r < 4; r++) {
            float v = pdr[r];
            v += __shfl_xor(v, 1, 16);
            v += __shfl_xor(v, 2, 16);
            v += __shfl_xor(v, 4, 16);
            v += __shfl_xor(v, 8, 16);
            if (m == 0) {
                const int nd = nb0 + w * 16 + quad * 4 + r;
                if (nd < NN) atomicAdd(out + batch[nd], v + bout[0]);
            }
        }
    }
}

extern "C" void kernel_launch(void* const* d_in, const int* in_sizes, int n_in,
                              void* d_out, int out_size, void* d_ws, size_t ws_size,
                              hipStream_t stream)
{
    const float* nf   = (const float*)d_in[0];
    const float* ef   = (const float*)d_in[1];
    const int*   Esrc = (const int*)  d_in[2];
    const int*   Etgt = (const int*)  d_in[3];
    const int*   bat  = (const int*)  d_in[4];
    const float* Win  = (const float*)d_in[5];
    const float* bin_ = (const float*)d_in[6];
    const float* We1  = (const float*)d_in[7];
    const float* be1  = (const float*)d_in[8];
    const float* We2  = (const float*)d_in[9];
    const float* be2  = (const float*)d_in[10];
    const float* Wih  = (const float*)d_in[11];
    const float* bih  = (const float*)d_in[12];
    const float* Whh  = (const float*)d_in[13];
    const float* bhh  = (const float*)d_in[14];
    const float* Wout = (const float*)d_in[15];
    const float* bout = (const float*)d_in[16];

    char* ws = (char*)d_ws;
    float*  x     = (float*)(ws);                // 12,800,000 B
    float*  msgf  = (float*)(ws + 12800000);     // 25,600,000 B
    __half* xh    = (__half*)(ws + 38400000);    //  6,400,000 B
    __half* ehh   = (__half*)(ws + 44800000);    // 12,800,000 B
    __half* Bp    = (__half*)(ws + 57600000);    //    532,480 B
    __half* WG    = (__half*)(ws + 58132480);    //     49,152 B
    int*    cnt   = (int*)   (ws + 58181632);    //    200,016 B
    int*    off   = (int*)   (ws + 58381648);    //    200,016 B
    int*    wpos  = (int*)   (ws + 58581664);    //    200,016 B
    int*    inv   = (int*)   (ws + 58781680);    //    400,000 B
    __half* aggh  = (__half*)(ws + 59181680);    //  6,400,000 B
    int*    bsum  = (int*)   (ws + 65581680);    //      1,024 B
    int*    bscan = (int*)   (ws + 65582704);    //      1,024 B

    hipMemsetAsync(d_out, 0, NB * sizeof(float), stream);
    hipMemsetAsync(cnt, 0, (NN + 1) * sizeof(int), stream);

    prep_kernel<<<PREP_GRID, 256, 0, stream>>>(
        nf, Win, bin_, x, xh, ef, We1, be1, ehh, We2, be2, Bp, Wih, Whh, WG);

    hist_kernel<<<(NE + 255) / 256, 256, 0, stream>>>(Etgt, cnt);
    scanA_kernel<<<NBLK_SCAN, 256, 0, stream>>>(cnt, bsum);
    scanB_kernel<<<1, 256, 0, stream>>>(bsum, bscan, off);
    scanC_kernel<<<NBLK_SCAN, 256, 0, stream>>>(cnt, bscan, off, wpos);
    scatter_kernel<<<(NE + 255) / 256, 256, 0, stream>>>(Etgt, wpos, inv);

    for (int t = 0; t < 3; t++) {
        msg_kernel<<<(NE + 127) / 128, 256, 0, stream>>>(xh, ehh, Bp, Esrc, inv, msgf);
        segsum_kernel<<<(NN + 15) / 16, 256, 0, stream>>>(msgf, off, aggh);
        gru_kernel<<<(NN + 63) / 64, 256, 0, stream>>>(
            aggh, x, xh, WG, bih, bhh,
            Wout, bout, bat, (float*)d_out, (t == 2) ? 1 : 0);
    }
}